// Round 1
// baseline (798.832 us; speedup 1.0000x reference)
//
#include <hip/hip_runtime.h>
#include <hip/hip_bf16.h>

typedef unsigned short u16;
typedef __attribute__((ext_vector_type(8))) short short8;
typedef __attribute__((ext_vector_type(4))) float floatx4;

#define NB 4
#define NT 2048
#define ND 1024
#define NH 2048
#define NO 1024
#define NE 8
#define NTOK (NB * NT)   // 8192 tokens

#define BM 128
#define BN 128
#define BK 32
#define LDSP 40          // padded LDS leading dim (u16 units): 2-way bank alias only

__device__ __forceinline__ u16 f2bf(float f) {
  __hip_bfloat16 h = __float2bfloat16(f);
  return *reinterpret_cast<u16*>(&h);
}

// ---------------------------------------------------------------------------
// Transpose + fp32->bf16 convert: per-expert R x C (row-major) -> C x R bf16
// ---------------------------------------------------------------------------
__global__ __launch_bounds__(256) void transpose_cvt(
    const float* __restrict__ in, u16* __restrict__ out, int R, int C) {
  __shared__ float tile[32][33];
  int e = blockIdx.z;
  in  += (size_t)e * R * C;
  out += (size_t)e * R * C;
  int c0 = blockIdx.x * 32, r0 = blockIdx.y * 32;
  int tx = threadIdx.x & 31, ty = threadIdx.x >> 5;   // 32 x 8
#pragma unroll
  for (int i = 0; i < 4; ++i) {
    int r = r0 + ty + i * 8;
    tile[ty + i * 8][tx] = in[(size_t)r * C + c0 + tx];
  }
  __syncthreads();
#pragma unroll
  for (int i = 0; i < 4; ++i) {
    int c = c0 + ty + i * 8;
    out[(size_t)c * R + r0 + tx] = f2bf(tile[tx][ty + i * 8]);
  }
}

// ---------------------------------------------------------------------------
// Router: one block per token. Computes logits, top-2, gate weights,
// appends (token*2+slot, weight) to the expert's compacted list, and
// emits the bf16 copy of x.
// ---------------------------------------------------------------------------
__global__ __launch_bounds__(256) void router_kernel(
    const float* __restrict__ x, const float* __restrict__ Wg,
    const float* __restrict__ bg, u16* __restrict__ xbf,
    int* __restrict__ counts, int* __restrict__ entries,
    float* __restrict__ wts) {
  __shared__ float xs[ND];
  __shared__ float lg[NE];
  int tok = blockIdx.x;
  int t = threadIdx.x;

  float4 v = ((const float4*)(x + (size_t)tok * ND))[t];
  *(float4*)&xs[t * 4] = v;
  uint2 p;
  p.x = (unsigned)f2bf(v.x) | ((unsigned)f2bf(v.y) << 16);
  p.y = (unsigned)f2bf(v.z) | ((unsigned)f2bf(v.w) << 16);
  *(uint2*)(xbf + (size_t)tok * ND + t * 4) = p;
  __syncthreads();

  int e = t >> 5;        // 8 groups of 32 threads, one expert each
  int l32 = t & 31;
  float acc = 0.f;
#pragma unroll
  for (int i = 0; i < 32; ++i) {
    int d = l32 + i * 32;
    acc += xs[d] * Wg[d * NE + e];
  }
#pragma unroll
  for (int off = 16; off; off >>= 1) acc += __shfl_down(acc, off, 32);
  if (l32 == 0) lg[e] = acc + bg[e];
  __syncthreads();

  if (t == 0) {
    float best = -1e30f, second = -1e30f;
    int e0 = 0, e1 = 0;
    for (int i = 0; i < NE; ++i) {
      float L = lg[i];
      if (L > best) { second = best; e1 = e0; best = L; e0 = i; }
      else if (L > second) { second = L; e1 = i; }
    }
    // softmax + top-2 mask + L1 renorm collapses to a 2-way softmax
    float p1 = __expf(second - best);
    float inv = 1.f / (1.f + p1);
    float w0 = inv, w1 = p1 * inv;
    int pos0 = atomicAdd(&counts[e0], 1);
    entries[e0 * NTOK + pos0] = tok * 2;      wts[e0 * NTOK + pos0] = w0;
    int pos1 = atomicAdd(&counts[e1], 1);
    entries[e1 * NTOK + pos1] = tok * 2 + 1;  wts[e1 * NTOK + pos1] = w1;
  }
}

// ---------------------------------------------------------------------------
// GEMM1: for expert e, rows = gathered x tokens, C = relu(X*W1 + b1) -> hbuf
// A: xbf [token][ND], B: w1t [e][NH][ND] (B^T layout), 128x128 tile, BK=32
// ---------------------------------------------------------------------------
__global__ __launch_bounds__(256) void gemm1_kernel(
    const u16* __restrict__ xbf, const u16* __restrict__ w1t,
    const float* __restrict__ b1, const int* __restrict__ counts,
    const int* __restrict__ entries, u16* __restrict__ hbuf) {
  int e = blockIdx.z;
  int cnt = counts[e];
  int m0 = blockIdx.y * BM;
  if (m0 >= cnt) return;
  int n0 = blockIdx.x * BN;
  int rem = cnt - m0; if (rem > BM) rem = BM;

  __shared__ u16 As[BM * LDSP];
  __shared__ u16 Bs[BN * LDSP];
  __shared__ int ent_s[BM];

  int t = threadIdx.x;
  if (t < BM) ent_s[t] = (t < rem) ? entries[e * NTOK + m0 + t] : -1;
  __syncthreads();

  const u16* Bbase = w1t + (size_t)e * NH * ND + (size_t)n0 * ND;

  floatx4 acc[4][4] = {};
  int lane = t & 63, wv = t >> 6;
  int waveM = (wv >> 1) * 64, waveN = (wv & 1) * 64;
  int rA = lane & 15, quad = lane >> 4;

  for (int k0 = 0; k0 < ND; k0 += BK) {
#pragma unroll
    for (int c = t; c < 512; c += 256) {            // A tile: 128 rows x 32 k
      int row = c >> 2, part = c & 3;
      int4 vv = {0, 0, 0, 0};
      int ent = ent_s[row];
      if (ent >= 0)
        vv = ((const int4*)(xbf + (size_t)(ent >> 1) * ND + k0))[part];
      *(int4*)&As[row * LDSP + part * 8] = vv;
    }
#pragma unroll
    for (int c = t; c < 512; c += 256) {            // B tile
      int row = c >> 2, part = c & 3;
      int4 vv = ((const int4*)(Bbase + (size_t)row * ND + k0))[part];
      *(int4*)&Bs[row * LDSP + part * 8] = vv;
    }
    __syncthreads();
    short8 a[4], b[4];
#pragma unroll
    for (int i = 0; i < 4; ++i)
      a[i] = *(const short8*)&As[(waveM + i * 16 + rA) * LDSP + quad * 8];
#pragma unroll
    for (int j = 0; j < 4; ++j)
      b[j] = *(const short8*)&Bs[(waveN + j * 16 + rA) * LDSP + quad * 8];
#pragma unroll
    for (int i = 0; i < 4; ++i)
#pragma unroll
      for (int j = 0; j < 4; ++j)
        acc[i][j] = __builtin_amdgcn_mfma_f32_16x16x32_bf16(a[i], b[j], acc[i][j], 0, 0, 0);
    __syncthreads();
  }

#pragma unroll
  for (int i = 0; i < 4; ++i)
#pragma unroll
    for (int r = 0; r < 4; ++r) {
      int lm = waveM + i * 16 + quad * 4 + r;
      if (lm >= rem) continue;
      int ent = ent_s[lm];
      u16* dst = hbuf + (size_t)ent * NH + n0;
#pragma unroll
      for (int j = 0; j < 4; ++j) {
        int col = waveN + j * 16 + rA;
        float v = acc[i][j][r] + b1[e * NH + n0 + col];
        dst[col] = f2bf(fmaxf(v, 0.f));
      }
    }
}

// ---------------------------------------------------------------------------
// GEMM2: C = (H*W2 + b2) * gate_w, atomically accumulated into out[token]
// A: hbuf [entry][NH], B: w2t [e][NO][NH] (B^T layout)
// ---------------------------------------------------------------------------
__global__ __launch_bounds__(256) void gemm2_kernel(
    const u16* __restrict__ hbuf, const u16* __restrict__ w2t,
    const float* __restrict__ b2, const int* __restrict__ counts,
    const int* __restrict__ entries, const float* __restrict__ wts,
    float* __restrict__ out) {
  int e = blockIdx.z;
  int cnt = counts[e];
  int m0 = blockIdx.y * BM;
  if (m0 >= cnt) return;
  int n0 = blockIdx.x * BN;
  int rem = cnt - m0; if (rem > BM) rem = BM;

  __shared__ u16 As[BM * LDSP];
  __shared__ u16 Bs[BN * LDSP];
  __shared__ int ent_s[BM];
  __shared__ float w_s[BM];

  int t = threadIdx.x;
  if (t < BM) {
    if (t < rem) {
      ent_s[t] = entries[e * NTOK + m0 + t];
      w_s[t] = wts[e * NTOK + m0 + t];
    } else ent_s[t] = -1;
  }
  __syncthreads();

  const u16* Bbase = w2t + (size_t)e * NO * NH + (size_t)n0 * NH;

  floatx4 acc[4][4] = {};
  int lane = t & 63, wv = t >> 6;
  int waveM = (wv >> 1) * 64, waveN = (wv & 1) * 64;
  int rA = lane & 15, quad = lane >> 4;

  for (int k0 = 0; k0 < NH; k0 += BK) {
#pragma unroll
    for (int c = t; c < 512; c += 256) {
      int row = c >> 2, part = c & 3;
      int4 vv = {0, 0, 0, 0};
      int ent = ent_s[row];
      if (ent >= 0)
        vv = ((const int4*)(hbuf + (size_t)ent * NH + k0))[part];
      *(int4*)&As[row * LDSP + part * 8] = vv;
    }
#pragma unroll
    for (int c = t; c < 512; c += 256) {
      int row = c >> 2, part = c & 3;
      int4 vv = ((const int4*)(Bbase + (size_t)row * NH + k0))[part];
      *(int4*)&Bs[row * LDSP + part * 8] = vv;
    }
    __syncthreads();
    short8 a[4], b[4];
#pragma unroll
    for (int i = 0; i < 4; ++i)
      a[i] = *(const short8*)&As[(waveM + i * 16 + rA) * LDSP + quad * 8];
#pragma unroll
    for (int j = 0; j < 4; ++j)
      b[j] = *(const short8*)&Bs[(waveN + j * 16 + rA) * LDSP + quad * 8];
#pragma unroll
    for (int i = 0; i < 4; ++i)
#pragma unroll
      for (int j = 0; j < 4; ++j)
        acc[i][j] = __builtin_amdgcn_mfma_f32_16x16x32_bf16(a[i], b[j], acc[i][j], 0, 0, 0);
    __syncthreads();
  }

#pragma unroll
  for (int i = 0; i < 4; ++i)
#pragma unroll
    for (int r = 0; r < 4; ++r) {
      int lm = waveM + i * 16 + quad * 4 + r;
      if (lm >= rem) continue;
      int ent = ent_s[lm];
      int tok = ent >> 1;
      float w = w_s[lm];
      float* dst = out + (size_t)tok * NO + n0;
#pragma unroll
      for (int j = 0; j < 4; ++j) {
        int col = waveN + j * 16 + rA;
        float v = (acc[i][j][r] + b2[e * NO + n0 + col]) * w;
        atomicAdd(&dst[col], v);
      }
    }
}

// ---------------------------------------------------------------------------
extern "C" void kernel_launch(void* const* d_in, const int* in_sizes, int n_in,
                              void* d_out, int out_size, void* d_ws, size_t ws_size,
                              hipStream_t stream) {
  (void)in_sizes; (void)n_in; (void)out_size; (void)ws_size;
  const float* x  = (const float*)d_in[0];
  const float* Wg = (const float*)d_in[2];
  const float* bg = (const float*)d_in[3];
  const float* W1 = (const float*)d_in[4];
  const float* b1 = (const float*)d_in[5];
  const float* W2 = (const float*)d_in[6];
  const float* b2 = (const float*)d_in[7];
  float* out = (float*)d_out;

  char* ws = (char*)d_ws;
  size_t off = 0;
  int*   counts  = (int*)(ws + off);   off += 256;
  int*   entries = (int*)(ws + off);   off += (size_t)NE * NTOK * 4;     // 256 KB
  float* wts     = (float*)(ws + off); off += (size_t)NE * NTOK * 4;     // 256 KB
  u16*   xbf     = (u16*)(ws + off);   off += (size_t)NTOK * ND * 2;     // 16 MB
  u16*   w1t     = (u16*)(ws + off);   off += (size_t)NE * NH * ND * 2;  // 32 MB
  u16*   w2t     = (u16*)(ws + off);   off += (size_t)NE * NO * NH * 2;  // 32 MB
  u16*   hbuf    = (u16*)(ws + off);   off += (size_t)NTOK * 2 * NH * 2; // 64 MB

  hipMemsetAsync(counts, 0, 256, stream);
  hipMemsetAsync(out, 0, (size_t)NTOK * NO * sizeof(float), stream);

  transpose_cvt<<<dim3(NH / 32, ND / 32, NE), 256, 0, stream>>>(W1, w1t, ND, NH);
  transpose_cvt<<<dim3(NO / 32, NH / 32, NE), 256, 0, stream>>>(W2, w2t, NH, NO);
  router_kernel<<<NTOK, 256, 0, stream>>>(x, Wg, bg, xbf, counts, entries, wts);
  gemm1_kernel<<<dim3(NH / BN, NTOK / BM, NE), 256, 0, stream>>>(xbf, w1t, b1, counts, entries, hbuf);
  gemm2_kernel<<<dim3(NO / BN, NTOK / BM, NE), 256, 0, stream>>>(hbuf, w2t, b2, counts, entries, wts, out);
}

// Round 2
// 614.516 us; speedup vs baseline: 1.2999x; 1.2999x over previous
//
#include <hip/hip_runtime.h>
#include <hip/hip_bf16.h>

typedef unsigned short u16;
typedef __attribute__((ext_vector_type(8))) short short8;
typedef __attribute__((ext_vector_type(4))) float floatx4;

#define NB 4
#define NT 2048
#define ND 1024
#define NH 2048
#define NO 1024
#define NE 8
#define NTOK (NB * NT)   // 8192 tokens

#define BM 128
#define BN 128
#define BK 32

__device__ __forceinline__ u16 f2bf(float f) {
  __hip_bfloat16 h = __float2bfloat16(f);
  return *reinterpret_cast<u16*>(&h);
}

__device__ __forceinline__ float bf2f(unsigned u) {
  return __uint_as_float(u << 16);
}

// async 16B global->LDS (direct-to-LDS DMA, lane i lands at ldsbase + i*16)
__device__ __forceinline__ void async16(const u16* g, u16* l) {
  __builtin_amdgcn_global_load_lds(
      (const __attribute__((address_space(1))) void*)g,
      (__attribute__((address_space(3))) void*)l, 16, 0, 0);
}

// ---------------------------------------------------------------------------
// Transpose + fp32->bf16: per-expert RxC row-major -> CxR bf16.
// 64x64 tiles: float4 reads, uint2 (4x u16) writes -> 128B contiguous runs.
// ---------------------------------------------------------------------------
__global__ __launch_bounds__(256) void transpose_cvt(
    const float* __restrict__ in, u16* __restrict__ out, int R, int C) {
  __shared__ float tile[64][65];
  int e = blockIdx.z;
  in  += (size_t)e * R * C;
  out += (size_t)e * R * C;
  int c0 = blockIdx.x * 64, r0 = blockIdx.y * 64;
  int t = threadIdx.x;
#pragma unroll
  for (int i = 0; i < 4; ++i) {
    int idx = t + i * 256;                  // 0..1023 = 64 r x 16 cq
    int r = idx >> 4, cq = idx & 15;
    float4 v = *(const float4*)&in[(size_t)(r0 + r) * C + c0 + cq * 4];
    tile[r][cq * 4 + 0] = v.x; tile[r][cq * 4 + 1] = v.y;
    tile[r][cq * 4 + 2] = v.z; tile[r][cq * 4 + 3] = v.w;
  }
  __syncthreads();
#pragma unroll
  for (int i = 0; i < 4; ++i) {
    int idx = t + i * 256;                  // 64 c x 16 rq
    int c = idx >> 4, rq = idx & 15;
    uint2 p;
    p.x = (unsigned)f2bf(tile[rq * 4 + 0][c]) | ((unsigned)f2bf(tile[rq * 4 + 1][c]) << 16);
    p.y = (unsigned)f2bf(tile[rq * 4 + 2][c]) | ((unsigned)f2bf(tile[rq * 4 + 3][c]) << 16);
    *(uint2*)&out[(size_t)(c0 + c) * R + r0 + rq * 4] = p;
  }
}

// ---------------------------------------------------------------------------
// Router: one block per token. Logits, top-2, 2-way-softmax weights,
// compacted per-expert lists, bf16 copy of x.
// ---------------------------------------------------------------------------
__global__ __launch_bounds__(256) void router_kernel(
    const float* __restrict__ x, const float* __restrict__ Wg,
    const float* __restrict__ bg, u16* __restrict__ xbf,
    int* __restrict__ counts, int* __restrict__ entries,
    float* __restrict__ wts) {
  __shared__ float xs[ND];
  __shared__ float lg[NE];
  int tok = blockIdx.x;
  int t = threadIdx.x;

  float4 v = ((const float4*)(x + (size_t)tok * ND))[t];
  *(float4*)&xs[t * 4] = v;
  uint2 p;
  p.x = (unsigned)f2bf(v.x) | ((unsigned)f2bf(v.y) << 16);
  p.y = (unsigned)f2bf(v.z) | ((unsigned)f2bf(v.w) << 16);
  *(uint2*)(xbf + (size_t)tok * ND + t * 4) = p;
  __syncthreads();

  int e = t >> 5;
  int l32 = t & 31;
  float acc = 0.f;
#pragma unroll
  for (int i = 0; i < 32; ++i) {
    int d = l32 + i * 32;
    acc += xs[d] * Wg[d * NE + e];
  }
#pragma unroll
  for (int off = 16; off; off >>= 1) acc += __shfl_down(acc, off, 32);
  if (l32 == 0) lg[e] = acc + bg[e];
  __syncthreads();

  if (t == 0) {
    float best = -1e30f, second = -1e30f;
    int e0 = 0, e1 = 0;
    for (int i = 0; i < NE; ++i) {
      float L = lg[i];
      if (L > best) { second = best; e1 = e0; best = L; e0 = i; }
      else if (L > second) { second = L; e1 = i; }
    }
    float p1 = __expf(second - best);
    float inv = 1.f / (1.f + p1);
    int pos0 = atomicAdd(&counts[e0], 1);
    entries[e0 * NTOK + pos0] = tok * 2;      wts[e0 * NTOK + pos0] = inv;
    int pos1 = atomicAdd(&counts[e1], 1);
    entries[e1 * NTOK + pos1] = tok * 2 + 1;  wts[e1 * NTOK + pos1] = p1 * inv;
  }
}

// ---------------------------------------------------------------------------
// GEMM1: relu(X*W1 + b1) -> hbuf (bf16). m97-style: global_load_lds staging,
// unpadded tiles with k-chunk XOR swizzle, fixed fragment pointers.
// ---------------------------------------------------------------------------
__global__ __launch_bounds__(256) void gemm1_kernel(
    const u16* __restrict__ xbf, const u16* __restrict__ w1t,
    const float* __restrict__ b1, const int* __restrict__ counts,
    const int* __restrict__ entries, u16* __restrict__ hbuf) {
  int e = blockIdx.z;
  int cnt = counts[e];
  int m0 = blockIdx.y * BM;
  if (m0 >= cnt) return;
  int n0 = blockIdx.x * BN;
  int rem = cnt - m0; if (rem > BM) rem = BM;

  __shared__ u16 As[BM * BK];   // 8 KB
  __shared__ u16 Bs[BN * BK];   // 8 KB
  __shared__ int ent_s[BM];

  int t = threadIdx.x;
  if (t < BM) ent_s[t] = (t < rem) ? entries[e * NTOK + m0 + t] : entries[e * NTOK];
  __syncthreads();

  int lane = t & 63, wv = t >> 6;
  // staging: wave w covers rows [w*32, w*32+32), 2 instrs of 16 rows
  int r0s = wv * 32 + (lane >> 2);
  int r1s = r0s + 16;
  int pg0 = ((lane & 3) ^ (r0s & 3)) * 8;   // swizzled k-chunk (u16 units)
  int pg1 = ((lane & 3) ^ (r1s & 3)) * 8;
  const u16* gA0 = xbf + (size_t)(ent_s[r0s] >> 1) * ND + pg0;
  const u16* gA1 = xbf + (size_t)(ent_s[r1s] >> 1) * ND + pg1;
  const u16* Bbase = w1t + (size_t)e * NH * ND + (size_t)n0 * ND;
  const u16* gB0 = Bbase + (size_t)r0s * ND + pg0;
  const u16* gB1 = Bbase + (size_t)r1s * ND + pg1;
  u16* lA0 = As + (wv * 32) * BK;           // wave-uniform LDS bases
  u16* lA1 = As + (wv * 32 + 16) * BK;
  u16* lB0 = Bs + (wv * 32) * BK;
  u16* lB1 = Bs + (wv * 32 + 16) * BK;

  int waveM = (wv >> 1) * 64, waveN = (wv & 1) * 64;
  int rA = lane & 15, quad = lane >> 4;
  int xq = (quad ^ (rA & 3)) * 8;           // read-side swizzle (u16 units)
  const short8* aP[4]; const short8* bP[4];
#pragma unroll
  for (int i = 0; i < 4; ++i) {
    aP[i] = (const short8*)&As[(waveM + i * 16 + rA) * BK + xq];
    bP[i] = (const short8*)&Bs[(waveN + i * 16 + rA) * BK + xq];
  }

  floatx4 acc[4][4] = {};
  for (int k0 = 0; k0 < ND; k0 += BK) {
    async16(gA0 + k0, lA0);
    async16(gA1 + k0, lA1);
    async16(gB0 + k0, lB0);
    async16(gB1 + k0, lB1);
    __syncthreads();
    short8 a[4], b[4];
#pragma unroll
    for (int i = 0; i < 4; ++i) { a[i] = *aP[i]; b[i] = *bP[i]; }
#pragma unroll
    for (int i = 0; i < 4; ++i)
#pragma unroll
      for (int j = 0; j < 4; ++j)
        acc[i][j] = __builtin_amdgcn_mfma_f32_16x16x32_bf16(a[i], b[j], acc[i][j], 0, 0, 0);
    __syncthreads();
  }

#pragma unroll
  for (int i = 0; i < 4; ++i)
#pragma unroll
    for (int r = 0; r < 4; ++r) {
      int lm = waveM + i * 16 + quad * 4 + r;
      if (lm >= rem) continue;
      int ent = ent_s[lm];
      u16* dst = hbuf + (size_t)ent * NH + n0;
#pragma unroll
      for (int j = 0; j < 4; ++j) {
        int col = waveN + j * 16 + rA;
        float v = acc[i][j][r] + b1[e * NH + n0 + col];
        dst[col] = f2bf(fmaxf(v, 0.f));
      }
    }
}

// ---------------------------------------------------------------------------
// GEMM2: eo[entry] = (H*W2 + b2) * gate_w (bf16, plain stores; no atomics)
// ---------------------------------------------------------------------------
__global__ __launch_bounds__(256) void gemm2_kernel(
    const u16* __restrict__ hbuf, const u16* __restrict__ w2t,
    const float* __restrict__ b2, const int* __restrict__ counts,
    const int* __restrict__ entries, const float* __restrict__ wts,
    u16* __restrict__ eo) {
  int e = blockIdx.z;
  int cnt = counts[e];
  int m0 = blockIdx.y * BM;
  if (m0 >= cnt) return;
  int n0 = blockIdx.x * BN;
  int rem = cnt - m0; if (rem > BM) rem = BM;

  __shared__ u16 As[BM * BK];
  __shared__ u16 Bs[BN * BK];
  __shared__ int ent_s[BM];
  __shared__ float w_s[BM];

  int t = threadIdx.x;
  if (t < BM) {
    int src = (t < rem) ? (e * NTOK + m0 + t) : (e * NTOK);
    ent_s[t] = entries[src];
    w_s[t] = wts[src];
  }
  __syncthreads();

  int lane = t & 63, wv = t >> 6;
  int r0s = wv * 32 + (lane >> 2);
  int r1s = r0s + 16;
  int pg0 = ((lane & 3) ^ (r0s & 3)) * 8;
  int pg1 = ((lane & 3) ^ (r1s & 3)) * 8;
  const u16* gA0 = hbuf + (size_t)ent_s[r0s] * NH + pg0;
  const u16* gA1 = hbuf + (size_t)ent_s[r1s] * NH + pg1;
  const u16* Bbase = w2t + (size_t)e * NO * NH + (size_t)n0 * NH;
  const u16* gB0 = Bbase + (size_t)r0s * NH + pg0;
  const u16* gB1 = Bbase + (size_t)r1s * NH + pg1;
  u16* lA0 = As + (wv * 32) * BK;
  u16* lA1 = As + (wv * 32 + 16) * BK;
  u16* lB0 = Bs + (wv * 32) * BK;
  u16* lB1 = Bs + (wv * 32 + 16) * BK;

  int waveM = (wv >> 1) * 64, waveN = (wv & 1) * 64;
  int rA = lane & 15, quad = lane >> 4;
  int xq = (quad ^ (rA & 3)) * 8;
  const short8* aP[4]; const short8* bP[4];
#pragma unroll
  for (int i = 0; i < 4; ++i) {
    aP[i] = (const short8*)&As[(waveM + i * 16 + rA) * BK + xq];
    bP[i] = (const short8*)&Bs[(waveN + i * 16 + rA) * BK + xq];
  }

  floatx4 acc[4][4] = {};
  for (int k0 = 0; k0 < NH; k0 += BK) {
    async16(gA0 + k0, lA0);
    async16(gA1 + k0, lA1);
    async16(gB0 + k0, lB0);
    async16(gB1 + k0, lB1);
    __syncthreads();
    short8 a[4], b[4];
#pragma unroll
    for (int i = 0; i < 4; ++i) { a[i] = *aP[i]; b[i] = *bP[i]; }
#pragma unroll
    for (int i = 0; i < 4; ++i)
#pragma unroll
      for (int j = 0; j < 4; ++j)
        acc[i][j] = __builtin_amdgcn_mfma_f32_16x16x32_bf16(a[i], b[j], acc[i][j], 0, 0, 0);
    __syncthreads();
  }

#pragma unroll
  for (int i = 0; i < 4; ++i)
#pragma unroll
    for (int r = 0; r < 4; ++r) {
      int lm = waveM + i * 16 + quad * 4 + r;
      if (lm >= rem) continue;
      int ent = ent_s[lm];
      float w = w_s[lm];
      u16* dst = eo + (size_t)ent * NO + n0;
#pragma unroll
      for (int j = 0; j < 4; ++j) {
        int col = waveN + j * 16 + rA;
        float v = (acc[i][j][r] + b2[e * NO + n0 + col]) * w;
        dst[col] = f2bf(v);
      }
    }
}

// ---------------------------------------------------------------------------
// Combine: out[tok] = eo[2*tok] + eo[2*tok+1]   (weights already applied)
// ---------------------------------------------------------------------------
__global__ __launch_bounds__(256) void combine_kernel(
    const u16* __restrict__ eo, float* __restrict__ out) {
  size_t idx = (size_t)blockIdx.x * 256 + threadIdx.x;  // one per 4 outputs
  size_t tok = idx >> 8;                                // NO/4 = 256 quads/token
  int oq = (int)(idx & 255) * 4;
  const u16* p0 = eo + (tok * 2) * NO + oq;
  const u16* p1 = p0 + NO;
  uint2 ua = *(const uint2*)p0;
  uint2 ub = *(const uint2*)p1;
  float4 o;
  o.x = bf2f(ua.x & 0xffff) + bf2f(ub.x & 0xffff);
  o.y = bf2f(ua.x >> 16)    + bf2f(ub.x >> 16);
  o.z = bf2f(ua.y & 0xffff) + bf2f(ub.y & 0xffff);
  o.w = bf2f(ua.y >> 16)    + bf2f(ub.y >> 16);
  *(float4*)&out[tok * NO + oq] = o;
}

// ---------------------------------------------------------------------------
extern "C" void kernel_launch(void* const* d_in, const int* in_sizes, int n_in,
                              void* d_out, int out_size, void* d_ws, size_t ws_size,
                              hipStream_t stream) {
  (void)in_sizes; (void)n_in; (void)out_size; (void)ws_size;
  const float* x  = (const float*)d_in[0];
  const float* Wg = (const float*)d_in[2];
  const float* bg = (const float*)d_in[3];
  const float* W1 = (const float*)d_in[4];
  const float* b1 = (const float*)d_in[5];
  const float* W2 = (const float*)d_in[6];
  const float* b2 = (const float*)d_in[7];
  float* out = (float*)d_out;

  char* ws = (char*)d_ws;
  size_t off = 0;
  int*   counts  = (int*)(ws + off);   off += 256;
  int*   entries = (int*)(ws + off);   off += (size_t)NE * NTOK * 4;     // 256 KB
  float* wts     = (float*)(ws + off); off += (size_t)NE * NTOK * 4;     // 256 KB
  u16*   xbf     = (u16*)(ws + off);   off += (size_t)NTOK * ND * 2;     // 16 MB
  u16*   w1t     = (u16*)(ws + off);   off += (size_t)NE * NH * ND * 2;  // 32 MB
  u16*   w2t     = (u16*)(ws + off);   off += (size_t)NE * NO * NH * 2;  // 32 MB
  u16*   hbuf    = (u16*)(ws + off);   off += (size_t)NTOK * 2 * NH * 2; // 64 MB
  u16*   eo      = w1t;  // alias: w1t dead after gemm1; both 32 MB

  hipMemsetAsync(counts, 0, 256, stream);

  transpose_cvt<<<dim3(NH / 64, ND / 64, NE), 256, 0, stream>>>(W1, w1t, ND, NH);
  transpose_cvt<<<dim3(NO / 64, NH / 64, NE), 256, 0, stream>>>(W2, w2t, NH, NO);
  router_kernel<<<NTOK, 256, 0, stream>>>(x, Wg, bg, xbf, counts, entries, wts);
  gemm1_kernel<<<dim3(NH / BN, NTOK / BM, NE), 256, 0, stream>>>(xbf, w1t, b1, counts, entries, hbuf);
  gemm2_kernel<<<dim3(NO / BN, NTOK / BM, NE), 256, 0, stream>>>(hbuf, w2t, b2, counts, entries, wts, eo);
  combine_kernel<<<(NTOK * NO / 4) / 256, 256, 0, stream>>>(eo, out);
}

// Round 3
// 522.786 us; speedup vs baseline: 1.5280x; 1.1755x over previous
//
#include <hip/hip_runtime.h>
#include <hip/hip_bf16.h>

typedef unsigned short u16;
typedef __attribute__((ext_vector_type(8))) short short8;
typedef __attribute__((ext_vector_type(4))) float floatx4;

#define NB 4
#define NT 2048
#define ND 1024
#define NH 2048
#define NO 1024
#define NE 8
#define NTOK (NB * NT)   // 8192 tokens

#define BM 128
#define BN 128
#define BK 32

__device__ __forceinline__ u16 f2bf(float f) {
  __hip_bfloat16 h = __float2bfloat16(f);
  return *reinterpret_cast<u16*>(&h);
}

__device__ __forceinline__ float bf2f(unsigned u) {
  return __uint_as_float(u << 16);
}

// async 16B global->LDS (direct-to-LDS DMA, lane i lands at ldsbase + i*16)
__device__ __forceinline__ void async16(const u16* g, u16* l) {
  __builtin_amdgcn_global_load_lds(
      (const __attribute__((address_space(1))) void*)g,
      (__attribute__((address_space(3))) void*)l, 16, 0, 0);
}

// ---------------------------------------------------------------------------
// Transpose + fp32->bf16: per-expert RxC row-major -> CxR bf16.
// ---------------------------------------------------------------------------
__global__ __launch_bounds__(256) void transpose_cvt(
    const float* __restrict__ in, u16* __restrict__ out, int R, int C) {
  __shared__ float tile[64][65];
  int e = blockIdx.z;
  in  += (size_t)e * R * C;
  out += (size_t)e * R * C;
  int c0 = blockIdx.x * 64, r0 = blockIdx.y * 64;
  int t = threadIdx.x;
#pragma unroll
  for (int i = 0; i < 4; ++i) {
    int idx = t + i * 256;                  // 64 r x 16 cq
    int r = idx >> 4, cq = idx & 15;
    float4 v = *(const float4*)&in[(size_t)(r0 + r) * C + c0 + cq * 4];
    tile[r][cq * 4 + 0] = v.x; tile[r][cq * 4 + 1] = v.y;
    tile[r][cq * 4 + 2] = v.z; tile[r][cq * 4 + 3] = v.w;
  }
  __syncthreads();
#pragma unroll
  for (int i = 0; i < 4; ++i) {
    int idx = t + i * 256;                  // 64 c x 16 rq
    int c = idx >> 4, rq = idx & 15;
    uint2 p;
    p.x = (unsigned)f2bf(tile[rq * 4 + 0][c]) | ((unsigned)f2bf(tile[rq * 4 + 1][c]) << 16);
    p.y = (unsigned)f2bf(tile[rq * 4 + 2][c]) | ((unsigned)f2bf(tile[rq * 4 + 3][c]) << 16);
    *(uint2*)&out[(size_t)(c0 + c) * R + r0 + rq * 4] = p;
  }
}

// ---------------------------------------------------------------------------
// Router (flat): 16 tokens/block, 16 lanes/token. Fuses x->bf16 conversion,
// 8-expert logits in registers, shuffle-reduce, leader top-2 + scatter.
// ---------------------------------------------------------------------------
__global__ __launch_bounds__(256) void router_kernel(
    const float* __restrict__ x, const float* __restrict__ Wg,
    const float* __restrict__ bg, u16* __restrict__ xbf,
    int* __restrict__ counts, int* __restrict__ entries,
    float* __restrict__ wts) {
  int t = threadIdx.x;
  int tok = blockIdx.x * 16 + (t >> 4);
  int l16 = t & 15;

  float acc[8] = {};
  const float* xrow = x + (size_t)tok * ND;
  u16* xbrow = xbf + (size_t)tok * ND;
#pragma unroll
  for (int i = 0; i < 16; ++i) {
    int d0 = l16 * 4 + i * 64;
    float4 xv = *(const float4*)&xrow[d0];
    uint2 p;
    p.x = (unsigned)f2bf(xv.x) | ((unsigned)f2bf(xv.y) << 16);
    p.y = (unsigned)f2bf(xv.z) | ((unsigned)f2bf(xv.w) << 16);
    *(uint2*)&xbrow[d0] = p;
    const float* wr = Wg + (size_t)d0 * NE;
#pragma unroll
    for (int j = 0; j < 4; ++j) {
      float xs = (j == 0) ? xv.x : (j == 1) ? xv.y : (j == 2) ? xv.z : xv.w;
      float4 w0 = *(const float4*)&wr[j * NE];
      float4 w1 = *(const float4*)&wr[j * NE + 4];
      acc[0] += xs * w0.x; acc[1] += xs * w0.y;
      acc[2] += xs * w0.z; acc[3] += xs * w0.w;
      acc[4] += xs * w1.x; acc[5] += xs * w1.y;
      acc[6] += xs * w1.z; acc[7] += xs * w1.w;
    }
  }
#pragma unroll
  for (int off = 8; off; off >>= 1)
#pragma unroll
    for (int k = 0; k < 8; ++k) acc[k] += __shfl_down(acc[k], off, 16);

  if (l16 == 0) {
    float best = -1e30f, second = -1e30f;
    int e0 = 0, e1 = 0;
#pragma unroll
    for (int i = 0; i < NE; ++i) {
      float L = acc[i] + bg[i];
      if (L > best) { second = best; e1 = e0; best = L; e0 = i; }
      else if (L > second) { second = L; e1 = i; }
    }
    float p1 = __expf(second - best);
    float inv = 1.f / (1.f + p1);
    int pos0 = atomicAdd(&counts[e0], 1);
    entries[e0 * NTOK + pos0] = tok * 2;      wts[e0 * NTOK + pos0] = inv;
    int pos1 = atomicAdd(&counts[e1], 1);
    entries[e1 * NTOK + pos1] = tok * 2 + 1;  wts[e1 * NTOK + pos1] = p1 * inv;
  }
}

// ---------------------------------------------------------------------------
// GEMM1: relu(X*W1 + b1) -> hbuf (bf16). m97-style staging.
// ---------------------------------------------------------------------------
__global__ __launch_bounds__(256) void gemm1_kernel(
    const u16* __restrict__ xbf, const u16* __restrict__ w1t,
    const float* __restrict__ b1, const int* __restrict__ counts,
    const int* __restrict__ entries, u16* __restrict__ hbuf) {
  int e = blockIdx.z;
  int cnt = counts[e];
  int m0 = blockIdx.y * BM;
  if (m0 >= cnt) return;
  int n0 = blockIdx.x * BN;
  int rem = cnt - m0; if (rem > BM) rem = BM;

  __shared__ u16 As[BM * BK];   // 8 KB
  __shared__ u16 Bs[BN * BK];   // 8 KB
  __shared__ int ent_s[BM];

  int t = threadIdx.x;
  if (t < BM) ent_s[t] = (t < rem) ? entries[e * NTOK + m0 + t] : entries[e * NTOK];
  __syncthreads();

  int lane = t & 63, wv = t >> 6;
  int r0s = wv * 32 + (lane >> 2);
  int r1s = r0s + 16;
  int pg0 = ((lane & 3) ^ (r0s & 3)) * 8;   // swizzled k-chunk (u16 units)
  int pg1 = ((lane & 3) ^ (r1s & 3)) * 8;
  const u16* gA0 = xbf + (size_t)(ent_s[r0s] >> 1) * ND + pg0;
  const u16* gA1 = xbf + (size_t)(ent_s[r1s] >> 1) * ND + pg1;
  const u16* Bbase = w1t + (size_t)e * NH * ND + (size_t)n0 * ND;
  const u16* gB0 = Bbase + (size_t)r0s * ND + pg0;
  const u16* gB1 = Bbase + (size_t)r1s * ND + pg1;
  u16* lA0 = As + (wv * 32) * BK;
  u16* lA1 = As + (wv * 32 + 16) * BK;
  u16* lB0 = Bs + (wv * 32) * BK;
  u16* lB1 = Bs + (wv * 32 + 16) * BK;

  int waveM = (wv >> 1) * 64, waveN = (wv & 1) * 64;
  int rA = lane & 15, quad = lane >> 4;
  int xq = (quad ^ (rA & 3)) * 8;           // read-side swizzle
  const short8* aP[4]; const short8* bP[4];
#pragma unroll
  for (int i = 0; i < 4; ++i) {
    aP[i] = (const short8*)&As[(waveM + i * 16 + rA) * BK + xq];
    bP[i] = (const short8*)&Bs[(waveN + i * 16 + rA) * BK + xq];
  }

  floatx4 acc[4][4] = {};
  for (int k0 = 0; k0 < ND; k0 += BK) {
    async16(gA0 + k0, lA0);
    async16(gA1 + k0, lA1);
    async16(gB0 + k0, lB0);
    async16(gB1 + k0, lB1);
    __syncthreads();
    short8 a[4], b[4];
#pragma unroll
    for (int i = 0; i < 4; ++i) { a[i] = *aP[i]; b[i] = *bP[i]; }
#pragma unroll
    for (int i = 0; i < 4; ++i)
#pragma unroll
      for (int j = 0; j < 4; ++j)
        acc[i][j] = __builtin_amdgcn_mfma_f32_16x16x32_bf16(a[i], b[j], acc[i][j], 0, 0, 0);
    __syncthreads();
  }

#pragma unroll
  for (int i = 0; i < 4; ++i)
#pragma unroll
    for (int r = 0; r < 4; ++r) {
      int lm = waveM + i * 16 + quad * 4 + r;
      if (lm >= rem) continue;
      int ent = ent_s[lm];
      u16* dst = hbuf + (size_t)ent * NH + n0;
#pragma unroll
      for (int j = 0; j < 4; ++j) {
        int col = waveN + j * 16 + rA;
        float v = acc[i][j][r] + b1[e * NH + n0 + col];
        dst[col] = f2bf(fmaxf(v, 0.f));
      }
    }
}

// ---------------------------------------------------------------------------
// GEMM2: eo[entry] = (H*W2 + b2) * gate_w (bf16, plain stores; no atomics)
// ---------------------------------------------------------------------------
__global__ __launch_bounds__(256) void gemm2_kernel(
    const u16* __restrict__ hbuf, const u16* __restrict__ w2t,
    const float* __restrict__ b2, const int* __restrict__ counts,
    const int* __restrict__ entries, const float* __restrict__ wts,
    u16* __restrict__ eo) {
  int e = blockIdx.z;
  int cnt = counts[e];
  int m0 = blockIdx.y * BM;
  if (m0 >= cnt) return;
  int n0 = blockIdx.x * BN;
  int rem = cnt - m0; if (rem > BM) rem = BM;

  __shared__ u16 As[BM * BK];
  __shared__ u16 Bs[BN * BK];
  __shared__ int ent_s[BM];
  __shared__ float w_s[BM];

  int t = threadIdx.x;
  if (t < BM) {
    int src = (t < rem) ? (e * NTOK + m0 + t) : (e * NTOK);
    ent_s[t] = entries[src];
    w_s[t] = wts[src];
  }
  __syncthreads();

  int lane = t & 63, wv = t >> 6;
  int r0s = wv * 32 + (lane >> 2);
  int r1s = r0s + 16;
  int pg0 = ((lane & 3) ^ (r0s & 3)) * 8;
  int pg1 = ((lane & 3) ^ (r1s & 3)) * 8;
  const u16* gA0 = hbuf + (size_t)ent_s[r0s] * NH + pg0;
  const u16* gA1 = hbuf + (size_t)ent_s[r1s] * NH + pg1;
  const u16* Bbase = w2t + (size_t)e * NO * NH + (size_t)n0 * NH;
  const u16* gB0 = Bbase + (size_t)r0s * NH + pg0;
  const u16* gB1 = Bbase + (size_t)r1s * NH + pg1;
  u16* lA0 = As + (wv * 32) * BK;
  u16* lA1 = As + (wv * 32 + 16) * BK;
  u16* lB0 = Bs + (wv * 32) * BK;
  u16* lB1 = Bs + (wv * 32 + 16) * BK;

  int waveM = (wv >> 1) * 64, waveN = (wv & 1) * 64;
  int rA = lane & 15, quad = lane >> 4;
  int xq = (quad ^ (rA & 3)) * 8;
  const short8* aP[4]; const short8* bP[4];
#pragma unroll
  for (int i = 0; i < 4; ++i) {
    aP[i] = (const short8*)&As[(waveM + i * 16 + rA) * BK + xq];
    bP[i] = (const short8*)&Bs[(waveN + i * 16 + rA) * BK + xq];
  }

  floatx4 acc[4][4] = {};
  for (int k0 = 0; k0 < NH; k0 += BK) {
    async16(gA0 + k0, lA0);
    async16(gA1 + k0, lA1);
    async16(gB0 + k0, lB0);
    async16(gB1 + k0, lB1);
    __syncthreads();
    short8 a[4], b[4];
#pragma unroll
    for (int i = 0; i < 4; ++i) { a[i] = *aP[i]; b[i] = *bP[i]; }
#pragma unroll
    for (int i = 0; i < 4; ++i)
#pragma unroll
      for (int j = 0; j < 4; ++j)
        acc[i][j] = __builtin_amdgcn_mfma_f32_16x16x32_bf16(a[i], b[j], acc[i][j], 0, 0, 0);
    __syncthreads();
  }

#pragma unroll
  for (int i = 0; i < 4; ++i)
#pragma unroll
    for (int r = 0; r < 4; ++r) {
      int lm = waveM + i * 16 + quad * 4 + r;
      if (lm >= rem) continue;
      int ent = ent_s[lm];
      float w = w_s[lm];
      u16* dst = eo + (size_t)ent * NO + n0;
#pragma unroll
      for (int j = 0; j < 4; ++j) {
        int col = waveN + j * 16 + rA;
        float v = (acc[i][j][r] + b2[e * NO + n0 + col]) * w;
        dst[col] = f2bf(v);
      }
    }
}

// ---------------------------------------------------------------------------
// Combine: out[tok] = eo[2*tok] + eo[2*tok+1]
// ---------------------------------------------------------------------------
__global__ __launch_bounds__(256) void combine_kernel(
    const u16* __restrict__ eo, float* __restrict__ out) {
  size_t idx = (size_t)blockIdx.x * 256 + threadIdx.x;
  size_t tok = idx >> 8;
  int oq = (int)(idx & 255) * 4;
  const u16* p0 = eo + (tok * 2) * NO + oq;
  const u16* p1 = p0 + NO;
  uint2 ua = *(const uint2*)p0;
  uint2 ub = *(const uint2*)p1;
  float4 o;
  o.x = bf2f(ua.x & 0xffff) + bf2f(ub.x & 0xffff);
  o.y = bf2f(ua.x >> 16)    + bf2f(ub.x >> 16);
  o.z = bf2f(ua.y & 0xffff) + bf2f(ub.y & 0xffff);
  o.w = bf2f(ua.y >> 16)    + bf2f(ub.y >> 16);
  *(float4*)&out[tok * NO + oq] = o;
}

// ---------------------------------------------------------------------------
extern "C" void kernel_launch(void* const* d_in, const int* in_sizes, int n_in,
                              void* d_out, int out_size, void* d_ws, size_t ws_size,
                              hipStream_t stream) {
  (void)in_sizes; (void)n_in; (void)out_size; (void)ws_size;
  const float* x  = (const float*)d_in[0];
  const float* Wg = (const float*)d_in[2];
  const float* bg = (const float*)d_in[3];
  const float* W1 = (const float*)d_in[4];
  const float* b1 = (const float*)d_in[5];
  const float* W2 = (const float*)d_in[6];
  const float* b2 = (const float*)d_in[7];
  float* out = (float*)d_out;

  char* ws = (char*)d_ws;
  size_t off = 0;
  int*   counts  = (int*)(ws + off);   off += 256;
  int*   entries = (int*)(ws + off);   off += (size_t)NE * NTOK * 4;
  float* wts     = (float*)(ws + off); off += (size_t)NE * NTOK * 4;
  u16*   xbf     = (u16*)(ws + off);   off += (size_t)NTOK * ND * 2;
  u16*   w1t     = (u16*)(ws + off);   off += (size_t)NE * NH * ND * 2;
  u16*   w2t     = (u16*)(ws + off);   off += (size_t)NE * NO * NH * 2;
  u16*   hbuf    = (u16*)(ws + off);   off += (size_t)NTOK * 2 * NH * 2;
  u16*   eo      = w1t;  // alias: w1t dead after gemm1

  hipMemsetAsync(counts, 0, 256, stream);

  transpose_cvt<<<dim3(NH / 64, ND / 64, NE), 256, 0, stream>>>(W1, w1t, ND, NH);
  transpose_cvt<<<dim3(NO / 64, NH / 64, NE), 256, 0, stream>>>(W2, w2t, NH, NO);
  router_kernel<<<NTOK / 16, 256, 0, stream>>>(x, Wg, bg, xbf, counts, entries, wts);
  gemm1_kernel<<<dim3(NH / BN, NTOK / BM, NE), 256, 0, stream>>>(xbf, w1t, b1, counts, entries, hbuf);
  gemm2_kernel<<<dim3(NO / BN, NTOK / BM, NE), 256, 0, stream>>>(hbuf, w2t, b2, counts, entries, wts, eo);
  combine_kernel<<<(NTOK * NO / 4) / 256, 256, 0, stream>>>(eo, out);
}

// Round 4
// 487.308 us; speedup vs baseline: 1.6393x; 1.0728x over previous
//
#include <hip/hip_runtime.h>
#include <hip/hip_bf16.h>

typedef unsigned short u16;
typedef __attribute__((ext_vector_type(8))) short short8;
typedef __attribute__((ext_vector_type(4))) float floatx4;

#define NB 4
#define NT 2048
#define ND 1024
#define NH 2048
#define NO 1024
#define NE 8
#define NTOK (NB * NT)   // 8192 tokens

#define BM 128
#define BN 128
#define BK 32

__device__ __forceinline__ u16 f2bf(float f) {
  __hip_bfloat16 h = __float2bfloat16(f);
  return *reinterpret_cast<u16*>(&h);
}

__device__ __forceinline__ float bf2f(unsigned u) {
  return __uint_as_float(u << 16);
}

// async 16B global->LDS (direct-to-LDS DMA, lane i lands at ldsbase + i*16)
__device__ __forceinline__ void async16(const u16* g, u16* l) {
  __builtin_amdgcn_global_load_lds(
      (const __attribute__((address_space(1))) void*)g,
      (__attribute__((address_space(3))) void*)l, 16, 0, 0);
}

// ---------------------------------------------------------------------------
// Transpose + fp32->bf16: per-expert RxC row-major -> CxR bf16.
// ---------------------------------------------------------------------------
__global__ __launch_bounds__(256) void transpose_cvt(
    const float* __restrict__ in, u16* __restrict__ out, int R, int C) {
  __shared__ float tile[64][65];
  int e = blockIdx.z;
  in  += (size_t)e * R * C;
  out += (size_t)e * R * C;
  int c0 = blockIdx.x * 64, r0 = blockIdx.y * 64;
  int t = threadIdx.x;
#pragma unroll
  for (int i = 0; i < 4; ++i) {
    int idx = t + i * 256;                  // 64 r x 16 cq
    int r = idx >> 4, cq = idx & 15;
    float4 v = *(const float4*)&in[(size_t)(r0 + r) * C + c0 + cq * 4];
    tile[r][cq * 4 + 0] = v.x; tile[r][cq * 4 + 1] = v.y;
    tile[r][cq * 4 + 2] = v.z; tile[r][cq * 4 + 3] = v.w;
  }
  __syncthreads();
#pragma unroll
  for (int i = 0; i < 4; ++i) {
    int idx = t + i * 256;                  // 64 c x 16 rq
    int c = idx >> 4, rq = idx & 15;
    uint2 p;
    p.x = (unsigned)f2bf(tile[rq * 4 + 0][c]) | ((unsigned)f2bf(tile[rq * 4 + 1][c]) << 16);
    p.y = (unsigned)f2bf(tile[rq * 4 + 2][c]) | ((unsigned)f2bf(tile[rq * 4 + 3][c]) << 16);
    *(uint2*)&out[(size_t)(c0 + c) * R + r0 + rq * 4] = p;
  }
}

// ---------------------------------------------------------------------------
// Router (flat): 16 tokens/block, 16 lanes/token.
// ---------------------------------------------------------------------------
__global__ __launch_bounds__(256) void router_kernel(
    const float* __restrict__ x, const float* __restrict__ Wg,
    const float* __restrict__ bg, u16* __restrict__ xbf,
    int* __restrict__ counts, int* __restrict__ entries,
    float* __restrict__ wts) {
  int t = threadIdx.x;
  int tok = blockIdx.x * 16 + (t >> 4);
  int l16 = t & 15;

  float acc[8] = {};
  const float* xrow = x + (size_t)tok * ND;
  u16* xbrow = xbf + (size_t)tok * ND;
#pragma unroll
  for (int i = 0; i < 16; ++i) {
    int d0 = l16 * 4 + i * 64;
    float4 xv = *(const float4*)&xrow[d0];
    uint2 p;
    p.x = (unsigned)f2bf(xv.x) | ((unsigned)f2bf(xv.y) << 16);
    p.y = (unsigned)f2bf(xv.z) | ((unsigned)f2bf(xv.w) << 16);
    *(uint2*)&xbrow[d0] = p;
    const float* wr = Wg + (size_t)d0 * NE;
#pragma unroll
    for (int j = 0; j < 4; ++j) {
      float xs = (j == 0) ? xv.x : (j == 1) ? xv.y : (j == 2) ? xv.z : xv.w;
      float4 w0 = *(const float4*)&wr[j * NE];
      float4 w1 = *(const float4*)&wr[j * NE + 4];
      acc[0] += xs * w0.x; acc[1] += xs * w0.y;
      acc[2] += xs * w0.z; acc[3] += xs * w0.w;
      acc[4] += xs * w1.x; acc[5] += xs * w1.y;
      acc[6] += xs * w1.z; acc[7] += xs * w1.w;
    }
  }
#pragma unroll
  for (int off = 8; off; off >>= 1)
#pragma unroll
    for (int k = 0; k < 8; ++k) acc[k] += __shfl_down(acc[k], off, 16);

  if (l16 == 0) {
    float best = -1e30f, second = -1e30f;
    int e0 = 0, e1 = 0;
#pragma unroll
    for (int i = 0; i < NE; ++i) {
      float L = acc[i] + bg[i];
      if (L > best) { second = best; e1 = e0; best = L; e0 = i; }
      else if (L > second) { second = L; e1 = i; }
    }
    float p1 = __expf(second - best);
    float inv = 1.f / (1.f + p1);
    int pos0 = atomicAdd(&counts[e0], 1);
    entries[e0 * NTOK + pos0] = tok * 2;      wts[e0 * NTOK + pos0] = inv;
    int pos1 = atomicAdd(&counts[e1], 1);
    entries[e1 * NTOK + pos1] = tok * 2 + 1;  wts[e1 * NTOK + pos1] = p1 * inv;
  }
}

// ---------------------------------------------------------------------------
// GEMM1: relu(X*W1 + b1) -> hbuf. 1D grid, expert = blockIdx&7 (XCD-pinned),
// n innermost so A-tile-sharing blocks are adjacent on one XCD.
// ---------------------------------------------------------------------------
__global__ __launch_bounds__(256) void gemm1_kernel(
    const u16* __restrict__ xbf, const u16* __restrict__ w1t,
    const float* __restrict__ b1, const int* __restrict__ counts,
    const int* __restrict__ entries, u16* __restrict__ hbuf) {
  int b = blockIdx.x;
  int e = b & 7;
  int r = b >> 3;
  int m0 = (r >> 4) * BM;          // NH/BN = 16 n-tiles innermost
  int n0 = (r & 15) * BN;
  int cnt = counts[e];
  if (m0 >= cnt) return;
  int rem = cnt - m0; if (rem > BM) rem = BM;

  __shared__ u16 As[BM * BK];   // 8 KB
  __shared__ u16 Bs[BN * BK];   // 8 KB
  __shared__ int ent_s[BM];

  int t = threadIdx.x;
  if (t < BM) ent_s[t] = (t < rem) ? entries[e * NTOK + m0 + t] : entries[e * NTOK];
  __syncthreads();

  int lane = t & 63, wv = t >> 6;
  int r0s = wv * 32 + (lane >> 2);
  int r1s = r0s + 16;
  int pg0 = ((lane & 3) ^ (r0s & 3)) * 8;   // swizzled k-chunk (u16 units)
  int pg1 = ((lane & 3) ^ (r1s & 3)) * 8;
  const u16* gA0 = xbf + (size_t)(ent_s[r0s] >> 1) * ND + pg0;
  const u16* gA1 = xbf + (size_t)(ent_s[r1s] >> 1) * ND + pg1;
  const u16* Bbase = w1t + (size_t)e * NH * ND + (size_t)n0 * ND;
  const u16* gB0 = Bbase + (size_t)r0s * ND + pg0;
  const u16* gB1 = Bbase + (size_t)r1s * ND + pg1;
  u16* lA0 = As + (wv * 32) * BK;
  u16* lA1 = As + (wv * 32 + 16) * BK;
  u16* lB0 = Bs + (wv * 32) * BK;
  u16* lB1 = Bs + (wv * 32 + 16) * BK;

  int waveM = (wv >> 1) * 64, waveN = (wv & 1) * 64;
  int rA = lane & 15, quad = lane >> 4;
  int xq = (quad ^ (rA & 3)) * 8;           // read-side swizzle
  const short8* aP[4]; const short8* bP[4];
#pragma unroll
  for (int i = 0; i < 4; ++i) {
    aP[i] = (const short8*)&As[(waveM + i * 16 + rA) * BK + xq];
    bP[i] = (const short8*)&Bs[(waveN + i * 16 + rA) * BK + xq];
  }

  floatx4 acc[4][4] = {};
  for (int k0 = 0; k0 < ND; k0 += BK) {
    async16(gA0 + k0, lA0);
    async16(gA1 + k0, lA1);
    async16(gB0 + k0, lB0);
    async16(gB1 + k0, lB1);
    __syncthreads();
    short8 a[4], b[4];
#pragma unroll
    for (int i = 0; i < 4; ++i) { a[i] = *aP[i]; b[i] = *bP[i]; }
#pragma unroll
    for (int i = 0; i < 4; ++i)
#pragma unroll
      for (int j = 0; j < 4; ++j)
        acc[i][j] = __builtin_amdgcn_mfma_f32_16x16x32_bf16(a[i], b[j], acc[i][j], 0, 0, 0);
    __syncthreads();
  }

#pragma unroll
  for (int i = 0; i < 4; ++i)
#pragma unroll
    for (int rr = 0; rr < 4; ++rr) {
      int lm = waveM + i * 16 + quad * 4 + rr;
      if (lm >= rem) continue;
      int ent = ent_s[lm];
      u16* dst = hbuf + (size_t)ent * NH + n0;
#pragma unroll
      for (int j = 0; j < 4; ++j) {
        int col = waveN + j * 16 + rA;
        float v = acc[i][j][rr] + b1[e * NH + n0 + col];
        dst[col] = f2bf(fmaxf(v, 0.f));
      }
    }
}

// ---------------------------------------------------------------------------
// GEMM2: eo[entry] = (H*W2 + b2) * gate_w. Same XCD-pinned swizzle.
// ---------------------------------------------------------------------------
__global__ __launch_bounds__(256) void gemm2_kernel(
    const u16* __restrict__ hbuf, const u16* __restrict__ w2t,
    const float* __restrict__ b2, const int* __restrict__ counts,
    const int* __restrict__ entries, const float* __restrict__ wts,
    u16* __restrict__ eo) {
  int b = blockIdx.x;
  int e = b & 7;
  int r = b >> 3;
  int m0 = (r >> 3) * BM;          // NO/BN = 8 n-tiles innermost
  int n0 = (r & 7) * BN;
  int cnt = counts[e];
  if (m0 >= cnt) return;
  int rem = cnt - m0; if (rem > BM) rem = BM;

  __shared__ u16 As[BM * BK];
  __shared__ u16 Bs[BN * BK];
  __shared__ int ent_s[BM];
  __shared__ float w_s[BM];

  int t = threadIdx.x;
  if (t < BM) {
    int src = (t < rem) ? (e * NTOK + m0 + t) : (e * NTOK);
    ent_s[t] = entries[src];
    w_s[t] = wts[src];
  }
  __syncthreads();

  int lane = t & 63, wv = t >> 6;
  int r0s = wv * 32 + (lane >> 2);
  int r1s = r0s + 16;
  int pg0 = ((lane & 3) ^ (r0s & 3)) * 8;
  int pg1 = ((lane & 3) ^ (r1s & 3)) * 8;
  const u16* gA0 = hbuf + (size_t)ent_s[r0s] * NH + pg0;
  const u16* gA1 = hbuf + (size_t)ent_s[r1s] * NH + pg1;
  const u16* Bbase = w2t + (size_t)e * NO * NH + (size_t)n0 * NH;
  const u16* gB0 = Bbase + (size_t)r0s * NH + pg0;
  const u16* gB1 = Bbase + (size_t)r1s * NH + pg1;
  u16* lA0 = As + (wv * 32) * BK;
  u16* lA1 = As + (wv * 32 + 16) * BK;
  u16* lB0 = Bs + (wv * 32) * BK;
  u16* lB1 = Bs + (wv * 32 + 16) * BK;

  int waveM = (wv >> 1) * 64, waveN = (wv & 1) * 64;
  int rA = lane & 15, quad = lane >> 4;
  int xq = (quad ^ (rA & 3)) * 8;
  const short8* aP[4]; const short8* bP[4];
#pragma unroll
  for (int i = 0; i < 4; ++i) {
    aP[i] = (const short8*)&As[(waveM + i * 16 + rA) * BK + xq];
    bP[i] = (const short8*)&Bs[(waveN + i * 16 + rA) * BK + xq];
  }

  floatx4 acc[4][4] = {};
  for (int k0 = 0; k0 < NH; k0 += BK) {
    async16(gA0 + k0, lA0);
    async16(gA1 + k0, lA1);
    async16(gB0 + k0, lB0);
    async16(gB1 + k0, lB1);
    __syncthreads();
    short8 a[4], b[4];
#pragma unroll
    for (int i = 0; i < 4; ++i) { a[i] = *aP[i]; b[i] = *bP[i]; }
#pragma unroll
    for (int i = 0; i < 4; ++i)
#pragma unroll
      for (int j = 0; j < 4; ++j)
        acc[i][j] = __builtin_amdgcn_mfma_f32_16x16x32_bf16(a[i], b[j], acc[i][j], 0, 0, 0);
    __syncthreads();
  }

#pragma unroll
  for (int i = 0; i < 4; ++i)
#pragma unroll
    for (int rr = 0; rr < 4; ++rr) {
      int lm = waveM + i * 16 + quad * 4 + rr;
      if (lm >= rem) continue;
      int ent = ent_s[lm];
      float w = w_s[lm];
      u16* dst = eo + (size_t)ent * NO + n0;
#pragma unroll
      for (int j = 0; j < 4; ++j) {
        int col = waveN + j * 16 + rA;
        float v = (acc[i][j][rr] + b2[e * NO + n0 + col]) * w;
        dst[col] = f2bf(v);
      }
    }
}

// ---------------------------------------------------------------------------
// Combine: out[tok] = eo[2*tok] + eo[2*tok+1]
// ---------------------------------------------------------------------------
__global__ __launch_bounds__(256) void combine_kernel(
    const u16* __restrict__ eo, float* __restrict__ out) {
  size_t idx = (size_t)blockIdx.x * 256 + threadIdx.x;
  size_t tok = idx >> 8;
  int oq = (int)(idx & 255) * 4;
  const u16* p0 = eo + (tok * 2) * NO + oq;
  const u16* p1 = p0 + NO;
  uint2 ua = *(const uint2*)p0;
  uint2 ub = *(const uint2*)p1;
  float4 o;
  o.x = bf2f(ua.x & 0xffff) + bf2f(ub.x & 0xffff);
  o.y = bf2f(ua.x >> 16)    + bf2f(ub.x >> 16);
  o.z = bf2f(ua.y & 0xffff) + bf2f(ub.y & 0xffff);
  o.w = bf2f(ua.y >> 16)    + bf2f(ub.y >> 16);
  *(float4*)&out[tok * NO + oq] = o;
}

// ---------------------------------------------------------------------------
extern "C" void kernel_launch(void* const* d_in, const int* in_sizes, int n_in,
                              void* d_out, int out_size, void* d_ws, size_t ws_size,
                              hipStream_t stream) {
  (void)in_sizes; (void)n_in; (void)out_size; (void)ws_size;
  const float* x  = (const float*)d_in[0];
  const float* Wg = (const float*)d_in[2];
  const float* bg = (const float*)d_in[3];
  const float* W1 = (const float*)d_in[4];
  const float* b1 = (const float*)d_in[5];
  const float* W2 = (const float*)d_in[6];
  const float* b2 = (const float*)d_in[7];
  float* out = (float*)d_out;

  char* ws = (char*)d_ws;
  size_t off = 0;
  int*   counts  = (int*)(ws + off);   off += 256;
  int*   entries = (int*)(ws + off);   off += (size_t)NE * NTOK * 4;
  float* wts     = (float*)(ws + off); off += (size_t)NE * NTOK * 4;
  u16*   xbf     = (u16*)(ws + off);   off += (size_t)NTOK * ND * 2;
  u16*   w1t     = (u16*)(ws + off);   off += (size_t)NE * NH * ND * 2;
  u16*   w2t     = (u16*)(ws + off);   off += (size_t)NE * NO * NH * 2;
  u16*   hbuf    = (u16*)(ws + off);   off += (size_t)NTOK * 2 * NH * 2;
  u16*   eo      = w1t;  // alias: w1t dead after gemm1

  hipMemsetAsync(counts, 0, 256, stream);

  transpose_cvt<<<dim3(NH / 64, ND / 64, NE), 256, 0, stream>>>(W1, w1t, ND, NH);
  transpose_cvt<<<dim3(NO / 64, NH / 64, NE), 256, 0, stream>>>(W2, w2t, NH, NO);
  router_kernel<<<NTOK / 16, 256, 0, stream>>>(x, Wg, bg, xbf, counts, entries, wts);
  gemm1_kernel<<<NE * (NTOK / BM) * (NH / BN), 256, 0, stream>>>(xbf, w1t, b1, counts, entries, hbuf);
  gemm2_kernel<<<NE * (NTOK / BM) * (NO / BN), 256, 0, stream>>>(hbuf, w2t, b2, counts, entries, wts, eo);
  combine_kernel<<<(NTOK * NO / 4) / 256, 256, 0, stream>>>(eo, out);
}

// Round 5
// 469.042 us; speedup vs baseline: 1.7031x; 1.0389x over previous
//
#include <hip/hip_runtime.h>
#include <hip/hip_bf16.h>

typedef unsigned short u16;
typedef __attribute__((ext_vector_type(8))) short short8;
typedef __attribute__((ext_vector_type(4))) float floatx4;

#define NB 4
#define NT 2048
#define ND 1024
#define NH 2048
#define NO 1024
#define NE 8
#define NTOK (NB * NT)   // 8192 tokens

#define BM 128
#define BN 128
#define BK 64            // u16 units; 128 B per LDS row

__device__ __forceinline__ u16 f2bf(float f) {
  __hip_bfloat16 h = __float2bfloat16(f);
  return *reinterpret_cast<u16*>(&h);
}

__device__ __forceinline__ float bf2f(unsigned u) {
  return __uint_as_float(u << 16);
}

// async 16B global->LDS (DMA: lane i lands at ldsbase + i*16)
__device__ __forceinline__ void async16(const u16* g, u16* l) {
  __builtin_amdgcn_global_load_lds(
      (const __attribute__((address_space(1))) void*)g,
      (__attribute__((address_space(3))) void*)l, 16, 0, 0);
}

// ---------------------------------------------------------------------------
// Transpose + fp32->bf16: per-expert RxC row-major -> CxR bf16.
// ---------------------------------------------------------------------------
__global__ __launch_bounds__(256) void transpose_cvt(
    const float* __restrict__ in, u16* __restrict__ out, int R, int C) {
  __shared__ float tile[64][65];
  int e = blockIdx.z;
  in  += (size_t)e * R * C;
  out += (size_t)e * R * C;
  int c0 = blockIdx.x * 64, r0 = blockIdx.y * 64;
  int t = threadIdx.x;
#pragma unroll
  for (int i = 0; i < 4; ++i) {
    int idx = t + i * 256;                  // 64 r x 16 cq
    int r = idx >> 4, cq = idx & 15;
    float4 v = *(const float4*)&in[(size_t)(r0 + r) * C + c0 + cq * 4];
    tile[r][cq * 4 + 0] = v.x; tile[r][cq * 4 + 1] = v.y;
    tile[r][cq * 4 + 2] = v.z; tile[r][cq * 4 + 3] = v.w;
  }
  __syncthreads();
#pragma unroll
  for (int i = 0; i < 4; ++i) {
    int idx = t + i * 256;                  // 64 c x 16 rq
    int c = idx >> 4, rq = idx & 15;
    uint2 p;
    p.x = (unsigned)f2bf(tile[rq * 4 + 0][c]) | ((unsigned)f2bf(tile[rq * 4 + 1][c]) << 16);
    p.y = (unsigned)f2bf(tile[rq * 4 + 2][c]) | ((unsigned)f2bf(tile[rq * 4 + 3][c]) << 16);
    *(uint2*)&out[(size_t)(c0 + c) * R + r0 + rq * 4] = p;
  }
}

// ---------------------------------------------------------------------------
// Router: 32 tokens/block, 8 lanes/token. Per-block LDS choice table;
// ONE atomicAdd per expert per block, counters padded to 128 B apart.
// ---------------------------------------------------------------------------
__global__ __launch_bounds__(256) void router_kernel(
    const float* __restrict__ x, const float* __restrict__ Wg,
    const float* __restrict__ bg, u16* __restrict__ xbf,
    int* __restrict__ counts, int* __restrict__ entries,
    float* __restrict__ wts) {
  __shared__ int   se0[32], se1[32];
  __shared__ float sw0[32], sw1[32];
  int t = threadIdx.x;
  int tl = t >> 3;                 // token slot 0..31
  int l8 = t & 7;
  int tok = blockIdx.x * 32 + tl;

  const float* xrow = x + (size_t)tok * ND;
  u16* xbrow = xbf + (size_t)tok * ND;
  float acc[8] = {};
#pragma unroll 4
  for (int i = 0; i < 32; ++i) {
    int d0 = l8 * 4 + i * 32;
    float4 xv = *(const float4*)&xrow[d0];
    uint2 p;
    p.x = (unsigned)f2bf(xv.x) | ((unsigned)f2bf(xv.y) << 16);
    p.y = (unsigned)f2bf(xv.z) | ((unsigned)f2bf(xv.w) << 16);
    *(uint2*)&xbrow[d0] = p;
    const float* wr = Wg + (size_t)d0 * NE;
#pragma unroll
    for (int j = 0; j < 4; ++j) {
      float xs = (j == 0) ? xv.x : (j == 1) ? xv.y : (j == 2) ? xv.z : xv.w;
      float4 w0 = *(const float4*)&wr[j * NE];
      float4 w1 = *(const float4*)&wr[j * NE + 4];
      acc[0] += xs * w0.x; acc[1] += xs * w0.y;
      acc[2] += xs * w0.z; acc[3] += xs * w0.w;
      acc[4] += xs * w1.x; acc[5] += xs * w1.y;
      acc[6] += xs * w1.z; acc[7] += xs * w1.w;
    }
  }
#pragma unroll
  for (int off = 4; off; off >>= 1)
#pragma unroll
    for (int k = 0; k < 8; ++k) acc[k] += __shfl_down(acc[k], off, 8);

  if (l8 == 0) {
    float best = -1e30f, second = -1e30f;
    int e0 = 0, e1 = 0;
#pragma unroll
    for (int i = 0; i < NE; ++i) {
      float L = acc[i] + bg[i];
      if (L > best) { second = best; e1 = e0; best = L; e0 = i; }
      else if (L > second) { second = L; e1 = i; }
    }
    float p1 = __expf(second - best);
    float inv = 1.f / (1.f + p1);
    se0[tl] = e0; se1[tl] = e1;
    sw0[tl] = inv; sw1[tl] = p1 * inv;
  }
  __syncthreads();

  if (t < NE) {
    int e = t;
    int c = 0;
#pragma unroll
    for (int k = 0; k < 32; ++k) c += (se0[k] == e) + (se1[k] == e);
    int pos = atomicAdd(&counts[e * 32], c);   // padded: 128 B per expert
    int base = blockIdx.x * 32;
    for (int k = 0; k < 32; ++k) {
      if (se0[k] == e) { entries[e * NTOK + pos] = (base + k) * 2;     wts[e * NTOK + pos] = sw0[k]; ++pos; }
      if (se1[k] == e) { entries[e * NTOK + pos] = (base + k) * 2 + 1; wts[e * NTOK + pos] = sw1[k]; ++pos; }
    }
  }
}

// ---------------------------------------------------------------------------
// GEMM1: relu(X*W1 + b1) -> hbuf. BK=64 (32 MFMA per barrier pair),
// full-128B LDS rows, chunk = g ^ (row&7) swizzle (conflict-free floor).
// XCD-pinned 1D grid: expert = blockIdx&7, n innermost.
// ---------------------------------------------------------------------------
__global__ __launch_bounds__(256) void gemm1_kernel(
    const u16* __restrict__ xbf, const u16* __restrict__ w1t,
    const float* __restrict__ b1, const int* __restrict__ counts,
    const int* __restrict__ entries, u16* __restrict__ hbuf) {
  int b = blockIdx.x;
  int e = b & 7;
  int r = b >> 3;
  int m0 = (r >> 4) * BM;          // NH/BN = 16 n-tiles innermost
  int n0 = (r & 15) * BN;
  int cnt = counts[e * 32];
  if (m0 >= cnt) return;
  int rem = cnt - m0; if (rem > BM) rem = BM;

  __shared__ u16 As[BM * BK];   // 16 KB
  __shared__ u16 Bs[BN * BK];   // 16 KB
  __shared__ int ent_s[BM];

  int t = threadIdx.x;
  if (t < BM) ent_s[t] = (t < rem) ? entries[e * NTOK + m0 + t] : entries[e * NTOK];
  __syncthreads();

  int lane = t & 63, wv = t >> 6;
  int srow = lane >> 3;            // 0..7
  int schunk = lane & 7;
  int pg = (schunk ^ srow) * 8;    // swizzled global k-chunk (u16)

  const u16* Bbase = w1t + (size_t)e * NH * ND + (size_t)n0 * ND;
  const u16* gA[4]; const u16* gB[4];
  u16 *lA[4], *lB[4];
#pragma unroll
  for (int j = 0; j < 4; ++j) {
    int rr = wv * 32 + j * 8 + srow;
    gA[j] = xbf + (size_t)(ent_s[rr] >> 1) * ND + pg;
    gB[j] = Bbase + (size_t)rr * ND + pg;
    lA[j] = As + (wv * 32 + j * 8) * BK;   // wave-uniform base
    lB[j] = Bs + (wv * 32 + j * 8) * BK;
  }

  int waveM = (wv >> 1) * 64, waveN = (wv & 1) * 64;
  int rA = lane & 15, quad = lane >> 4;
  const short8* aP[2][4]; const short8* bP[2][4];
#pragma unroll
  for (int kk = 0; kk < 2; ++kk)
#pragma unroll
    for (int i = 0; i < 4; ++i) {
      int cA = ((kk * 4 + quad) ^ (rA & 7)) * 8;
      aP[kk][i] = (const short8*)&As[(waveM + i * 16 + rA) * BK + cA];
      bP[kk][i] = (const short8*)&Bs[(waveN + i * 16 + rA) * BK + cA];
    }

  floatx4 acc[4][4] = {};
  for (int k0 = 0; k0 < ND; k0 += BK) {
#pragma unroll
    for (int j = 0; j < 4; ++j) async16(gA[j] + k0, lA[j]);
#pragma unroll
    for (int j = 0; j < 4; ++j) async16(gB[j] + k0, lB[j]);
    __syncthreads();
    short8 a[2][4], bb[2][4];
#pragma unroll
    for (int kk = 0; kk < 2; ++kk)
#pragma unroll
      for (int i = 0; i < 4; ++i) { a[kk][i] = *aP[kk][i]; bb[kk][i] = *bP[kk][i]; }
#pragma unroll
    for (int kk = 0; kk < 2; ++kk)
#pragma unroll
      for (int i = 0; i < 4; ++i)
#pragma unroll
        for (int j = 0; j < 4; ++j)
          acc[i][j] = __builtin_amdgcn_mfma_f32_16x16x32_bf16(a[kk][i], bb[kk][j], acc[i][j], 0, 0, 0);
    __syncthreads();
  }

#pragma unroll
  for (int i = 0; i < 4; ++i)
#pragma unroll
    for (int rr = 0; rr < 4; ++rr) {
      int lm = waveM + i * 16 + quad * 4 + rr;
      if (lm >= rem) continue;
      int ent = ent_s[lm];
      u16* dst = hbuf + (size_t)ent * NH + n0;
#pragma unroll
      for (int j = 0; j < 4; ++j) {
        int col = waveN + j * 16 + rA;
        float v = acc[i][j][rr] + b1[e * NH + n0 + col];
        dst[col] = f2bf(fmaxf(v, 0.f));
      }
    }
}

// ---------------------------------------------------------------------------
// GEMM2: eo[entry] = (H*W2 + b2) * gate_w. Same structure, K=NH.
// ---------------------------------------------------------------------------
__global__ __launch_bounds__(256) void gemm2_kernel(
    const u16* __restrict__ hbuf, const u16* __restrict__ w2t,
    const float* __restrict__ b2, const int* __restrict__ counts,
    const int* __restrict__ entries, const float* __restrict__ wts,
    u16* __restrict__ eo) {
  int b = blockIdx.x;
  int e = b & 7;
  int r = b >> 3;
  int m0 = (r >> 3) * BM;          // NO/BN = 8 n-tiles innermost
  int n0 = (r & 7) * BN;
  int cnt = counts[e * 32];
  if (m0 >= cnt) return;
  int rem = cnt - m0; if (rem > BM) rem = BM;

  __shared__ u16 As[BM * BK];
  __shared__ u16 Bs[BN * BK];
  __shared__ int ent_s[BM];
  __shared__ float w_s[BM];

  int t = threadIdx.x;
  if (t < BM) {
    int src = (t < rem) ? (e * NTOK + m0 + t) : (e * NTOK);
    ent_s[t] = entries[src];
    w_s[t] = wts[src];
  }
  __syncthreads();

  int lane = t & 63, wv = t >> 6;
  int srow = lane >> 3;
  int schunk = lane & 7;
  int pg = (schunk ^ srow) * 8;

  const u16* Bbase = w2t + (size_t)e * NO * NH + (size_t)n0 * NH;
  const u16* gA[4]; const u16* gB[4];
  u16 *lA[4], *lB[4];
#pragma unroll
  for (int j = 0; j < 4; ++j) {
    int rr = wv * 32 + j * 8 + srow;
    gA[j] = hbuf + (size_t)ent_s[rr] * NH + pg;
    gB[j] = Bbase + (size_t)rr * NH + pg;
    lA[j] = As + (wv * 32 + j * 8) * BK;
    lB[j] = Bs + (wv * 32 + j * 8) * BK;
  }

  int waveM = (wv >> 1) * 64, waveN = (wv & 1) * 64;
  int rA = lane & 15, quad = lane >> 4;
  const short8* aP[2][4]; const short8* bP[2][4];
#pragma unroll
  for (int kk = 0; kk < 2; ++kk)
#pragma unroll
    for (int i = 0; i < 4; ++i) {
      int cA = ((kk * 4 + quad) ^ (rA & 7)) * 8;
      aP[kk][i] = (const short8*)&As[(waveM + i * 16 + rA) * BK + cA];
      bP[kk][i] = (const short8*)&Bs[(waveN + i * 16 + rA) * BK + cA];
    }

  floatx4 acc[4][4] = {};
  for (int k0 = 0; k0 < NH; k0 += BK) {
#pragma unroll
    for (int j = 0; j < 4; ++j) async16(gA[j] + k0, lA[j]);
#pragma unroll
    for (int j = 0; j < 4; ++j) async16(gB[j] + k0, lB[j]);
    __syncthreads();
    short8 a[2][4], bb[2][4];
#pragma unroll
    for (int kk = 0; kk < 2; ++kk)
#pragma unroll
      for (int i = 0; i < 4; ++i) { a[kk][i] = *aP[kk][i]; bb[kk][i] = *bP[kk][i]; }
#pragma unroll
    for (int kk = 0; kk < 2; ++kk)
#pragma unroll
      for (int i = 0; i < 4; ++i)
#pragma unroll
        for (int j = 0; j < 4; ++j)
          acc[i][j] = __builtin_amdgcn_mfma_f32_16x16x32_bf16(a[kk][i], bb[kk][j], acc[i][j], 0, 0, 0);
    __syncthreads();
  }

#pragma unroll
  for (int i = 0; i < 4; ++i)
#pragma unroll
    for (int rr = 0; rr < 4; ++rr) {
      int lm = waveM + i * 16 + quad * 4 + rr;
      if (lm >= rem) continue;
      int ent = ent_s[lm];
      float w = w_s[lm];
      u16* dst = eo + (size_t)ent * NO + n0;
#pragma unroll
      for (int j = 0; j < 4; ++j) {
        int col = waveN + j * 16 + rA;
        float v = (acc[i][j][rr] + b2[e * NO + n0 + col]) * w;
        dst[col] = f2bf(v);
      }
    }
}

// ---------------------------------------------------------------------------
// Combine: out[tok] = eo[2*tok] + eo[2*tok+1]
// ---------------------------------------------------------------------------
__global__ __launch_bounds__(256) void combine_kernel(
    const u16* __restrict__ eo, float* __restrict__ out) {
  size_t idx = (size_t)blockIdx.x * 256 + threadIdx.x;
  size_t tok = idx >> 8;
  int oq = (int)(idx & 255) * 4;
  const u16* p0 = eo + (tok * 2) * NO + oq;
  const u16* p1 = p0 + NO;
  uint2 ua = *(const uint2*)p0;
  uint2 ub = *(const uint2*)p1;
  float4 o;
  o.x = bf2f(ua.x & 0xffff) + bf2f(ub.x & 0xffff);
  o.y = bf2f(ua.x >> 16)    + bf2f(ub.x >> 16);
  o.z = bf2f(ua.y & 0xffff) + bf2f(ub.y & 0xffff);
  o.w = bf2f(ua.y >> 16)    + bf2f(ub.y >> 16);
  *(float4*)&out[tok * NO + oq] = o;
}

// ---------------------------------------------------------------------------
extern "C" void kernel_launch(void* const* d_in, const int* in_sizes, int n_in,
                              void* d_out, int out_size, void* d_ws, size_t ws_size,
                              hipStream_t stream) {
  (void)in_sizes; (void)n_in; (void)out_size; (void)ws_size;
  const float* x  = (const float*)d_in[0];
  const float* Wg = (const float*)d_in[2];
  const float* bg = (const float*)d_in[3];
  const float* W1 = (const float*)d_in[4];
  const float* b1 = (const float*)d_in[5];
  const float* W2 = (const float*)d_in[6];
  const float* b2 = (const float*)d_in[7];
  float* out = (float*)d_out;

  char* ws = (char*)d_ws;
  size_t off = 0;
  int*   counts  = (int*)(ws + off);   off += NE * 32 * 4;               // padded
  int*   entries = (int*)(ws + off);   off += (size_t)NE * NTOK * 4;
  float* wts     = (float*)(ws + off); off += (size_t)NE * NTOK * 4;
  u16*   xbf     = (u16*)(ws + off);   off += (size_t)NTOK * ND * 2;
  u16*   w1t     = (u16*)(ws + off);   off += (size_t)NE * NH * ND * 2;
  u16*   w2t     = (u16*)(ws + off);   off += (size_t)NE * NO * NH * 2;
  u16*   hbuf    = (u16*)(ws + off);   off += (size_t)NTOK * 2 * NH * 2;
  u16*   eo      = w1t;  // alias: w1t dead after gemm1

  hipMemsetAsync(counts, 0, NE * 32 * 4, stream);

  transpose_cvt<<<dim3(NH / 64, ND / 64, NE), 256, 0, stream>>>(W1, w1t, ND, NH);
  transpose_cvt<<<dim3(NO / 64, NH / 64, NE), 256, 0, stream>>>(W2, w2t, NH, NO);
  router_kernel<<<NTOK / 32, 256, 0, stream>>>(x, Wg, bg, xbf, counts, entries, wts);
  gemm1_kernel<<<NE * (NTOK / BM) * (NH / BN), 256, 0, stream>>>(xbf, w1t, b1, counts, entries, hbuf);
  gemm2_kernel<<<NE * (NTOK / BM) * (NO / BN), 256, 0, stream>>>(hbuf, w2t, b2, counts, entries, wts, eo);
  combine_kernel<<<(NTOK * NO / 4) / 256, 256, 0, stream>>>(eo, out);
}

// Round 6
// 437.922 us; speedup vs baseline: 1.8241x; 1.0711x over previous
//
#include <hip/hip_runtime.h>
#include <hip/hip_bf16.h>

typedef unsigned short u16;
typedef __attribute__((ext_vector_type(8))) short short8;
typedef __attribute__((ext_vector_type(4))) float floatx4;

#define NB 4
#define NT 2048
#define ND 1024
#define NH 2048
#define NO 1024
#define NE 8
#define NTOK (NB * NT)   // 8192 tokens

#define BM 128
#define BN 128
#define BK 32            // u16 units; 64 B per LDS row

__device__ __forceinline__ u16 f2bf(float f) {
  __hip_bfloat16 h = __float2bfloat16(f);
  return *reinterpret_cast<u16*>(&h);
}

__device__ __forceinline__ float bf2f(unsigned u) {
  return __uint_as_float(u << 16);
}

// async 16B global->LDS (DMA: lane i lands at ldsbase + i*16)
__device__ __forceinline__ void async16(const u16* g, u16* l) {
  __builtin_amdgcn_global_load_lds(
      (const __attribute__((address_space(1))) void*)g,
      (__attribute__((address_space(3))) void*)l, 16, 0, 0);
}

// ---------------------------------------------------------------------------
// Transpose + fp32->bf16: per-expert RxC row-major -> CxR bf16.
// ---------------------------------------------------------------------------
__global__ __launch_bounds__(256) void transpose_cvt(
    const float* __restrict__ in, u16* __restrict__ out, int R, int C) {
  __shared__ float tile[64][65];
  int e = blockIdx.z;
  in  += (size_t)e * R * C;
  out += (size_t)e * R * C;
  int c0 = blockIdx.x * 64, r0 = blockIdx.y * 64;
  int t = threadIdx.x;
#pragma unroll
  for (int i = 0; i < 4; ++i) {
    int idx = t + i * 256;                  // 64 r x 16 cq
    int r = idx >> 4, cq = idx & 15;
    float4 v = *(const float4*)&in[(size_t)(r0 + r) * C + c0 + cq * 4];
    tile[r][cq * 4 + 0] = v.x; tile[r][cq * 4 + 1] = v.y;
    tile[r][cq * 4 + 2] = v.z; tile[r][cq * 4 + 3] = v.w;
  }
  __syncthreads();
#pragma unroll
  for (int i = 0; i < 4; ++i) {
    int idx = t + i * 256;                  // 64 c x 16 rq
    int c = idx >> 4, rq = idx & 15;
    uint2 p;
    p.x = (unsigned)f2bf(tile[rq * 4 + 0][c]) | ((unsigned)f2bf(tile[rq * 4 + 1][c]) << 16);
    p.y = (unsigned)f2bf(tile[rq * 4 + 2][c]) | ((unsigned)f2bf(tile[rq * 4 + 3][c]) << 16);
    *(uint2*)&out[(size_t)(c0 + c) * R + r0 + rq * 4] = p;
  }
}

// ---------------------------------------------------------------------------
// Router: 32 tokens/block, 8 lanes/token. Per-block LDS choice table;
// ONE atomicAdd per expert per block, counters padded to 128 B apart.
// ---------------------------------------------------------------------------
__global__ __launch_bounds__(256) void router_kernel(
    const float* __restrict__ x, const float* __restrict__ Wg,
    const float* __restrict__ bg, u16* __restrict__ xbf,
    int* __restrict__ counts, int* __restrict__ entries,
    float* __restrict__ wts) {
  __shared__ int   se0[32], se1[32];
  __shared__ float sw0[32], sw1[32];
  int t = threadIdx.x;
  int tl = t >> 3;                 // token slot 0..31
  int l8 = t & 7;
  int tok = blockIdx.x * 32 + tl;

  const float* xrow = x + (size_t)tok * ND;
  u16* xbrow = xbf + (size_t)tok * ND;
  float acc[8] = {};
#pragma unroll 4
  for (int i = 0; i < 32; ++i) {
    int d0 = l8 * 4 + i * 32;
    float4 xv = *(const float4*)&xrow[d0];
    uint2 p;
    p.x = (unsigned)f2bf(xv.x) | ((unsigned)f2bf(xv.y) << 16);
    p.y = (unsigned)f2bf(xv.z) | ((unsigned)f2bf(xv.w) << 16);
    *(uint2*)&xbrow[d0] = p;
    const float* wr = Wg + (size_t)d0 * NE;
#pragma unroll
    for (int j = 0; j < 4; ++j) {
      float xs = (j == 0) ? xv.x : (j == 1) ? xv.y : (j == 2) ? xv.z : xv.w;
      float4 w0 = *(const float4*)&wr[j * NE];
      float4 w1 = *(const float4*)&wr[j * NE + 4];
      acc[0] += xs * w0.x; acc[1] += xs * w0.y;
      acc[2] += xs * w0.z; acc[3] += xs * w0.w;
      acc[4] += xs * w1.x; acc[5] += xs * w1.y;
      acc[6] += xs * w1.z; acc[7] += xs * w1.w;
    }
  }
#pragma unroll
  for (int off = 4; off; off >>= 1)
#pragma unroll
    for (int k = 0; k < 8; ++k) acc[k] += __shfl_down(acc[k], off, 8);

  if (l8 == 0) {
    float best = -1e30f, second = -1e30f;
    int e0 = 0, e1 = 0;
#pragma unroll
    for (int i = 0; i < NE; ++i) {
      float L = acc[i] + bg[i];
      if (L > best) { second = best; e1 = e0; best = L; e0 = i; }
      else if (L > second) { second = L; e1 = i; }
    }
    float p1 = __expf(second - best);
    float inv = 1.f / (1.f + p1);
    se0[tl] = e0; se1[tl] = e1;
    sw0[tl] = inv; sw1[tl] = p1 * inv;
  }
  __syncthreads();

  if (t < NE) {
    int e = t;
    int c = 0;
#pragma unroll
    for (int k = 0; k < 32; ++k) c += (se0[k] == e) + (se1[k] == e);
    int pos = atomicAdd(&counts[e * 32], c);   // padded: 128 B per expert
    int base = blockIdx.x * 32;
    for (int k = 0; k < 32; ++k) {
      if (se0[k] == e) { entries[e * NTOK + pos] = (base + k) * 2;     wts[e * NTOK + pos] = sw0[k]; ++pos; }
      if (se1[k] == e) { entries[e * NTOK + pos] = (base + k) * 2 + 1; wts[e * NTOK + pos] = sw1[k]; ++pos; }
    }
  }
}

// ---------------------------------------------------------------------------
// GEMM1: relu(X*W1 + b1) -> hbuf. BK=32 (17 KB LDS, high occupancy) with
// conflict-free swizzle: phys chunk = logical chunk ^ ((row>>1)&3).
// Staging applies the permutation on the GLOBAL chunk select (per-lane ok);
// reads use quad ^ ((rA>>1)&3) -> 2 lanes/bank-position = free.
// XCD-pinned 1D grid: expert = blockIdx&7, n innermost.
// ---------------------------------------------------------------------------
__global__ __launch_bounds__(256) void gemm1_kernel(
    const u16* __restrict__ xbf, const u16* __restrict__ w1t,
    const float* __restrict__ b1, const int* __restrict__ counts,
    const int* __restrict__ entries, u16* __restrict__ hbuf) {
  int b = blockIdx.x;
  int e = b & 7;
  int r = b >> 3;
  int m0 = (r >> 4) * BM;          // NH/BN = 16 n-tiles innermost
  int n0 = (r & 15) * BN;
  int cnt = counts[e * 32];
  if (m0 >= cnt) return;
  int rem = cnt - m0; if (rem > BM) rem = BM;

  __shared__ u16 As[BM * BK];   // 8 KB
  __shared__ u16 Bs[BN * BK];   // 8 KB
  __shared__ int ent_s[BM];

  int t = threadIdx.x;
  if (t < BM) ent_s[t] = (t < rem) ? entries[e * NTOK + m0 + t] : entries[e * NTOK];
  __syncthreads();

  int lane = t & 63, wv = t >> 6;
  // staging: wave w covers tile-local rows [w*32, w*32+32), 2 instrs of 16 rows
  int rl0 = wv * 32 + (lane >> 2);         // tile-local row, group 0
  int rl1 = rl0 + 16;                      // group 1 (same (row>>1)&3 phase)
  int pg = (((lane & 3) ^ ((rl0 >> 1) & 3))) * 8;   // swizzled GLOBAL chunk (u16)
  const u16* gA0 = xbf + (size_t)(ent_s[rl0] >> 1) * ND + pg;
  const u16* gA1 = xbf + (size_t)(ent_s[rl1] >> 1) * ND + pg;
  const u16* Bbase = w1t + (size_t)e * NH * ND + (size_t)n0 * ND;
  const u16* gB0 = Bbase + (size_t)rl0 * ND + pg;
  const u16* gB1 = Bbase + (size_t)rl1 * ND + pg;
  u16* lA0 = As + (wv * 32) * BK;          // wave-uniform LDS bases
  u16* lA1 = As + (wv * 32 + 16) * BK;
  u16* lB0 = Bs + (wv * 32) * BK;
  u16* lB1 = Bs + (wv * 32 + 16) * BK;

  int waveM = (wv >> 1) * 64, waveN = (wv & 1) * 64;
  int rA = lane & 15, quad = lane >> 4;
  int cR = (quad ^ ((rA >> 1) & 3)) * 8;   // read-side phys chunk (u16)
  const short8* aP[4]; const short8* bP[4];
#pragma unroll
  for (int i = 0; i < 4; ++i) {
    aP[i] = (const short8*)&As[(waveM + i * 16 + rA) * BK + cR];
    bP[i] = (const short8*)&Bs[(waveN + i * 16 + rA) * BK + cR];
  }

  floatx4 acc[4][4] = {};
  for (int k0 = 0; k0 < ND; k0 += BK) {
    async16(gA0 + k0, lA0);
    async16(gA1 + k0, lA1);
    async16(gB0 + k0, lB0);
    async16(gB1 + k0, lB1);
    __syncthreads();
    short8 a[4], bb[4];
#pragma unroll
    for (int i = 0; i < 4; ++i) { a[i] = *aP[i]; bb[i] = *bP[i]; }
#pragma unroll
    for (int i = 0; i < 4; ++i)
#pragma unroll
      for (int j = 0; j < 4; ++j)
        acc[i][j] = __builtin_amdgcn_mfma_f32_16x16x32_bf16(a[i], bb[j], acc[i][j], 0, 0, 0);
    __syncthreads();
  }

#pragma unroll
  for (int i = 0; i < 4; ++i)
#pragma unroll
    for (int rr = 0; rr < 4; ++rr) {
      int lm = waveM + i * 16 + quad * 4 + rr;
      if (lm >= rem) continue;
      int ent = ent_s[lm];
      u16* dst = hbuf + (size_t)ent * NH + n0;
#pragma unroll
      for (int j = 0; j < 4; ++j) {
        int col = waveN + j * 16 + rA;
        float v = acc[i][j][rr] + b1[e * NH + n0 + col];
        dst[col] = f2bf(fmaxf(v, 0.f));
      }
    }
}

// ---------------------------------------------------------------------------
// GEMM2: eo[entry] = (H*W2 + b2) * gate_w. Same structure, K=NH.
// ---------------------------------------------------------------------------
__global__ __launch_bounds__(256) void gemm2_kernel(
    const u16* __restrict__ hbuf, const u16* __restrict__ w2t,
    const float* __restrict__ b2, const int* __restrict__ counts,
    const int* __restrict__ entries, const float* __restrict__ wts,
    u16* __restrict__ eo) {
  int b = blockIdx.x;
  int e = b & 7;
  int r = b >> 3;
  int m0 = (r >> 3) * BM;          // NO/BN = 8 n-tiles innermost
  int n0 = (r & 7) * BN;
  int cnt = counts[e * 32];
  if (m0 >= cnt) return;
  int rem = cnt - m0; if (rem > BM) rem = BM;

  __shared__ u16 As[BM * BK];
  __shared__ u16 Bs[BN * BK];
  __shared__ int ent_s[BM];
  __shared__ float w_s[BM];

  int t = threadIdx.x;
  if (t < BM) {
    int src = (t < rem) ? (e * NTOK + m0 + t) : (e * NTOK);
    ent_s[t] = entries[src];
    w_s[t] = wts[src];
  }
  __syncthreads();

  int lane = t & 63, wv = t >> 6;
  int rl0 = wv * 32 + (lane >> 2);
  int rl1 = rl0 + 16;
  int pg = (((lane & 3) ^ ((rl0 >> 1) & 3))) * 8;
  const u16* gA0 = hbuf + (size_t)ent_s[rl0] * NH + pg;
  const u16* gA1 = hbuf + (size_t)ent_s[rl1] * NH + pg;
  const u16* Bbase = w2t + (size_t)e * NO * NH + (size_t)n0 * NH;
  const u16* gB0 = Bbase + (size_t)rl0 * NH + pg;
  const u16* gB1 = Bbase + (size_t)rl1 * NH + pg;
  u16* lA0 = As + (wv * 32) * BK;
  u16* lA1 = As + (wv * 32 + 16) * BK;
  u16* lB0 = Bs + (wv * 32) * BK;
  u16* lB1 = Bs + (wv * 32 + 16) * BK;

  int waveM = (wv >> 1) * 64, waveN = (wv & 1) * 64;
  int rA = lane & 15, quad = lane >> 4;
  int cR = (quad ^ ((rA >> 1) & 3)) * 8;
  const short8* aP[4]; const short8* bP[4];
#pragma unroll
  for (int i = 0; i < 4; ++i) {
    aP[i] = (const short8*)&As[(waveM + i * 16 + rA) * BK + cR];
    bP[i] = (const short8*)&Bs[(waveN + i * 16 + rA) * BK + cR];
  }

  floatx4 acc[4][4] = {};
  for (int k0 = 0; k0 < NH; k0 += BK) {
    async16(gA0 + k0, lA0);
    async16(gA1 + k0, lA1);
    async16(gB0 + k0, lB0);
    async16(gB1 + k0, lB1);
    __syncthreads();
    short8 a[4], bb[4];
#pragma unroll
    for (int i = 0; i < 4; ++i) { a[i] = *aP[i]; bb[i] = *bP[i]; }
#pragma unroll
    for (int i = 0; i < 4; ++i)
#pragma unroll
      for (int j = 0; j < 4; ++j)
        acc[i][j] = __builtin_amdgcn_mfma_f32_16x16x32_bf16(a[i], bb[j], acc[i][j], 0, 0, 0);
    __syncthreads();
  }

#pragma unroll
  for (int i = 0; i < 4; ++i)
#pragma unroll
    for (int rr = 0; rr < 4; ++rr) {
      int lm = waveM + i * 16 + quad * 4 + rr;
      if (lm >= rem) continue;
      int ent = ent_s[lm];
      float w = w_s[lm];
      u16* dst = eo + (size_t)ent * NO + n0;
#pragma unroll
      for (int j = 0; j < 4; ++j) {
        int col = waveN + j * 16 + rA;
        float v = (acc[i][j][rr] + b2[e * NO + n0 + col]) * w;
        dst[col] = f2bf(v);
      }
    }
}

// ---------------------------------------------------------------------------
// Combine: out[tok] = eo[2*tok] + eo[2*tok+1]
// ---------------------------------------------------------------------------
__global__ __launch_bounds__(256) void combine_kernel(
    const u16* __restrict__ eo, float* __restrict__ out) {
  size_t idx = (size_t)blockIdx.x * 256 + threadIdx.x;
  size_t tok = idx >> 8;
  int oq = (int)(idx & 255) * 4;
  const u16* p0 = eo + (tok * 2) * NO + oq;
  const u16* p1 = p0 + NO;
  uint2 ua = *(const uint2*)p0;
  uint2 ub = *(const uint2*)p1;
  float4 o;
  o.x = bf2f(ua.x & 0xffff) + bf2f(ub.x & 0xffff);
  o.y = bf2f(ua.x >> 16)    + bf2f(ub.x >> 16);
  o.z = bf2f(ua.y & 0xffff) + bf2f(ub.y & 0xffff);
  o.w = bf2f(ua.y >> 16)    + bf2f(ub.y >> 16);
  *(float4*)&out[tok * NO + oq] = o;
}

// ---------------------------------------------------------------------------
extern "C" void kernel_launch(void* const* d_in, const int* in_sizes, int n_in,
                              void* d_out, int out_size, void* d_ws, size_t ws_size,
                              hipStream_t stream) {
  (void)in_sizes; (void)n_in; (void)out_size; (void)ws_size;
  const float* x  = (const float*)d_in[0];
  const float* Wg = (const float*)d_in[2];
  const float* bg = (const float*)d_in[3];
  const float* W1 = (const float*)d_in[4];
  const float* b1 = (const float*)d_in[5];
  const float* W2 = (const float*)d_in[6];
  const float* b2 = (const float*)d_in[7];
  float* out = (float*)d_out;

  char* ws = (char*)d_ws;
  size_t off = 0;
  int*   counts  = (int*)(ws + off);   off += NE * 32 * 4;               // padded
  int*   entries = (int*)(ws + off);   off += (size_t)NE * NTOK * 4;
  float* wts     = (float*)(ws + off); off += (size_t)NE * NTOK * 4;
  u16*   xbf     = (u16*)(ws + off);   off += (size_t)NTOK * ND * 2;
  u16*   w1t     = (u16*)(ws + off);   off += (size_t)NE * NH * ND * 2;
  u16*   w2t     = (u16*)(ws + off);   off += (size_t)NE * NO * NH * 2;
  u16*   hbuf    = (u16*)(ws + off);   off += (size_t)NTOK * 2 * NH * 2;
  u16*   eo      = w1t;  // alias: w1t dead after gemm1

  hipMemsetAsync(counts, 0, NE * 32 * 4, stream);

  transpose_cvt<<<dim3(NH / 64, ND / 64, NE), 256, 0, stream>>>(W1, w1t, ND, NH);
  transpose_cvt<<<dim3(NO / 64, NH / 64, NE), 256, 0, stream>>>(W2, w2t, NH, NO);
  router_kernel<<<NTOK / 32, 256, 0, stream>>>(x, Wg, bg, xbf, counts, entries, wts);
  gemm1_kernel<<<NE * (NTOK / BM) * (NH / BN), 256, 0, stream>>>(xbf, w1t, b1, counts, entries, hbuf);
  gemm2_kernel<<<NE * (NTOK / BM) * (NO / BN), 256, 0, stream>>>(hbuf, w2t, b2, counts, entries, wts, eo);
  combine_kernel<<<(NTOK * NO / 4) / 256, 256, 0, stream>>>(eo, out);
}